// Round 12
// baseline (1698.966 us; speedup 1.0000x reference)
//
#include <hip/hip_runtime.h>
#include <hip/hip_bf16.h>
#include <math.h>

#define NFEAT 500
#define KPAD  512
#define NHID  256
#define NCLS  64
#define KPOLY 10

typedef __attribute__((ext_vector_type(8))) short short8;
typedef __attribute__((ext_vector_type(4))) float f32x4;

__device__ inline unsigned short bf16_rn(float v) {
  unsigned u = __float_as_uint(v);
  return (unsigned short)((u + 0x7FFFu + ((u >> 16) & 1u)) >> 16);
}
__device__ inline float u2f_lo(unsigned u) { return __uint_as_float(u << 16); }
__device__ inline float u2f_hi(unsigned u) { return __uint_as_float(u & 0xFFFF0000u); }
__device__ inline unsigned pack2(float a, float b) {
  return (unsigned)bf16_rn(a) | ((unsigned)bf16_rn(b) << 16);
}
__device__ inline void split2(float v, unsigned short& hi, unsigned short& lo) {
  unsigned short h = bf16_rn(v);
  float vh = __uint_as_float(((unsigned)h) << 16);
  lo = bf16_rn(v - vh);
  hi = h;
}

// ---------- weight pre-conversion into MFMA fragment layout ----------
__global__ void conv_w1f(const float* __restrict__ W1, unsigned short* __restrict__ Fh,
                         unsigned short* __restrict__ Fl) {
  int i = blockIdx.x * 256 + threadIdx.x;
  if (i >= KPAD * NHID) return;
  int kg = i >> 11, c = (i >> 3) & 255, kin = i & 7;
  int k = kg * 8 + kin;
  float v = (k < NFEAT) ? W1[c * NFEAT + k] : 0.0f;
  unsigned short h, l;
  split2(v, h, l);
  Fh[i] = h; Fl[i] = l;
}
__global__ void conv_w2f(const float* __restrict__ W2, unsigned short* __restrict__ F) {
  int i = blockIdx.x * 256 + threadIdx.x;
  if (i >= NHID * NCLS) return;
  int kg = i >> 9, c = (i >> 3) & 63, kin = i & 7;
  int k = kg * 8 + kin;
  F[i] = bf16_rn(W2[c * NHID + k]);
}

// ------------------------- CSR build -------------------------
__global__ void edge_count(const int* __restrict__ ei, int E,
                           int* __restrict__ cnt, int* __restrict__ selfc) {
  int stride = gridDim.x * blockDim.x;
  for (int e = blockIdx.x * blockDim.x + threadIdx.x; e < E; e += stride) {
    int r = ei[e], c = ei[E + e];
    atomicAdd(&cnt[r], 1);
    if (r == c) atomicAdd(&selfc[r], 1);
  }
}

__global__ void make_dinv(const int* __restrict__ cnt, const int* __restrict__ selfc,
                          float* __restrict__ dinv, int n) {
  int i = blockIdx.x * blockDim.x + threadIdx.x;
  if (i < n) {
    int d = cnt[i] - selfc[i];
    dinv[i] = (d > 0) ? rsqrtf((float)d) : 0.0f;
  }
}

__global__ void scan_block(const int* __restrict__ cnt, int* __restrict__ rowptr,
                           int* __restrict__ bsums, int n) {
  __shared__ int s[256];
  int i = blockIdx.x * 256 + threadIdx.x;
  int v = (i < n) ? cnt[i] : 0;
  s[threadIdx.x] = v;
  __syncthreads();
  for (int off = 1; off < 256; off <<= 1) {
    int t = (threadIdx.x >= (unsigned)off) ? s[threadIdx.x - off] : 0;
    __syncthreads();
    s[threadIdx.x] += t;
    __syncthreads();
  }
  if (i < n) rowptr[i + 1] = s[threadIdx.x];
  if (threadIdx.x == 255) bsums[blockIdx.x] = s[255];
}

__global__ void scan_sums(int* __restrict__ bsums, int nb, int* __restrict__ rowptr) {
  if (threadIdx.x == 0 && blockIdx.x == 0) {
    int run = 0;
    for (int b = 0; b < nb; ++b) { int t = bsums[b]; bsums[b] = run; run += t; }
    rowptr[0] = 0;
  }
}

__global__ void scan_add(int* __restrict__ rowptr, const int* __restrict__ bsums, int n) {
  int i = blockIdx.x * 256 + threadIdx.x;
  if (i < n) rowptr[i + 1] += bsums[i >> 8];
}

__global__ void scatter_edges(const int* __restrict__ ei, int E,
                              const float* __restrict__ dinv,
                              const int* __restrict__ rowptr, int* __restrict__ cur,
                              int2* __restrict__ ecw) {
  int stride = gridDim.x * blockDim.x;
  for (int e = blockIdx.x * blockDim.x + threadIdx.x; e < E; e += stride) {
    int r = ei[e], c = ei[E + e];
    int pos = rowptr[r] + atomicAdd(&cur[r], 1);
    float wt = (r != c) ? (-dinv[r] * dinv[c]) : 0.0f;
    ecw[pos] = make_int2(c, __float_as_int(wt));
  }
}

// ------------------------- fused MLP via MFMA (bf16 hi/lo split) -------------------------
// Pipelined A staging (double-buffered LDS, 1 barrier/K-step); B frags from global.
// OUTPUT IS QUARTER-MAJOR: hout[(q*n + row)*16 + (ch&15)], q = ch>>4.
__global__ __launch_bounds__(256, 4) void mlp_mfma(
    const float* __restrict__ x, const unsigned short* __restrict__ W1Fh,
    const unsigned short* __restrict__ W1Fl, const unsigned short* __restrict__ W2F,
    unsigned short* __restrict__ hout, int n)
{
  __shared__ union {
    struct { unsigned short Ah[2][4][64][8], Al[2][4][64][8]; } g1;  // 16 KB
    struct { unsigned short A2[32][64][8]; } g2;                     // 32 KB
  } u;

  const int tid = threadIdx.x;
  const int w = tid >> 6;
  const int l = tid & 63;
  const int l15 = l & 15, l4 = l >> 4;
  const int row0 = blockIdx.x * 64;

  f32x4 acc[4][4];
  const f32x4 zf = {0.0f, 0.0f, 0.0f, 0.0f};
#pragma unroll
  for (int i = 0; i < 4; ++i)
#pragma unroll
    for (int j = 0; j < 4; ++j) acc[i][j] = zf;

  // prologue: stage tile 0 into buffer 0
#pragma unroll
  for (int s = 0; s < 2; ++s) {
    int f = tid + s * 256;
    int r = f >> 3, slot = f & 7;
    int gr = row0 + r, gk = slot * 4;
    float4 v = make_float4(0.f, 0.f, 0.f, 0.f);
    if (gr < n && gk + 3 < NFEAT)
      v = *(const float4*)&x[(size_t)gr * NFEAT + gk];
    unsigned short a0, a1, a2, a3, b0, b1, b2, b3;
    split2(v.x, a0, b0); split2(v.y, a1, b1); split2(v.z, a2, b2); split2(v.w, a3, b3);
    int kg = slot >> 1, kin0 = (slot & 1) * 4;
    *(uint2*)&u.g1.Ah[0][kg][r][kin0] =
        make_uint2((unsigned)a0 | ((unsigned)a1 << 16), (unsigned)a2 | ((unsigned)a3 << 16));
    *(uint2*)&u.g1.Al[0][kg][r][kin0] =
        make_uint2((unsigned)b0 | ((unsigned)b1 << 16), (unsigned)b2 | ((unsigned)b3 << 16));
  }
  __syncthreads();

  for (int t = 0; t < 16; ++t) {
    const int cur = t & 1;
    float4 va[2];
    if (t < 15) {
#pragma unroll
      for (int s = 0; s < 2; ++s) {
        int f = tid + s * 256;
        int r = f >> 3, slot = f & 7;
        int gr = row0 + r, gk = (t + 1) * 32 + slot * 4;
        va[s] = make_float4(0.f, 0.f, 0.f, 0.f);
        if (gr < n && gk + 3 < NFEAT)
          va[s] = *(const float4*)&x[(size_t)gr * NFEAT + gk];
      }
    }
    short8 bH[4], bL[4];
#pragma unroll
    for (int nf = 0; nf < 4; ++nf) {
      size_t bi = (size_t)t * 8192 + ((size_t)l4 * 256 + w * 64 + nf * 16 + l15) * 8;
      bH[nf] = *(const short8*)(W1Fh + bi);
      bL[nf] = *(const short8*)(W1Fl + bi);
    }
#pragma unroll
    for (int mf = 0; mf < 4; ++mf) {
      short8 aH = *(const short8*)&u.g1.Ah[cur][l4][mf * 16 + l15][0];
      short8 aL = *(const short8*)&u.g1.Al[cur][l4][mf * 16 + l15][0];
#pragma unroll
      for (int nf = 0; nf < 4; ++nf) {
        acc[mf][nf] = __builtin_amdgcn_mfma_f32_16x16x32_bf16(aH, bH[nf], acc[mf][nf], 0, 0, 0);
        acc[mf][nf] = __builtin_amdgcn_mfma_f32_16x16x32_bf16(aH, bL[nf], acc[mf][nf], 0, 0, 0);
        acc[mf][nf] = __builtin_amdgcn_mfma_f32_16x16x32_bf16(aL, bH[nf], acc[mf][nf], 0, 0, 0);
      }
    }
    if (t < 15) {
#pragma unroll
      for (int s = 0; s < 2; ++s) {
        int f = tid + s * 256;
        int r = f >> 3, slot = f & 7;
        unsigned short a0, a1, a2, a3, b0, b1, b2, b3;
        split2(va[s].x, a0, b0); split2(va[s].y, a1, b1);
        split2(va[s].z, a2, b2); split2(va[s].w, a3, b3);
        int kg = slot >> 1, kin0 = (slot & 1) * 4;
        *(uint2*)&u.g1.Ah[cur ^ 1][kg][r][kin0] =
            make_uint2((unsigned)a0 | ((unsigned)a1 << 16), (unsigned)a2 | ((unsigned)a3 << 16));
        *(uint2*)&u.g1.Al[cur ^ 1][kg][r][kin0] =
            make_uint2((unsigned)b0 | ((unsigned)b1 << 16), (unsigned)b2 | ((unsigned)b3 << 16));
      }
    }
    __syncthreads();
  }

#pragma unroll
  for (int mf = 0; mf < 4; ++mf)
#pragma unroll
    for (int nf = 0; nf < 4; ++nf) {
      int col = w * 64 + nf * 16 + l15;
      int kg = col >> 3, kin = col & 7;
#pragma unroll
      for (int j = 0; j < 4; ++j) {
        float vv = fmaxf(acc[mf][nf][j], 0.0f);
        u.g2.A2[kg][mf * 16 + l4 * 4 + j][kin] = bf16_rn(vv);
      }
    }
  __syncthreads();

  f32x4 acc2[4];
#pragma unroll
  for (int i = 0; i < 4; ++i) acc2[i] = zf;
#pragma unroll
  for (int ks = 0; ks < 8; ++ks) {
    short8 a2 = *(const short8*)&u.g2.A2[ks * 4 + l4][w * 16 + l15][0];
#pragma unroll
    for (int nf2 = 0; nf2 < 4; ++nf2) {
      size_t bi = ((size_t)(ks * 4 + l4) * 64 + nf2 * 16 + l15) * 8;
      short8 b2 = *(const short8*)(W2F + bi);
      acc2[nf2] = __builtin_amdgcn_mfma_f32_16x16x32_bf16(a2, b2, acc2[nf2], 0, 0, 0);
    }
  }
  // quarter-major store: ch = nf2*16 + l15 -> q == nf2, within == l15
#pragma unroll
  for (int nf2 = 0; nf2 < 4; ++nf2)
#pragma unroll
    for (int j = 0; j < 4; ++j) {
      int r = row0 + w * 16 + l4 * 4 + j;
      if (r < n) hout[((size_t)nf2 * n + r) * 16 + l15] = bf16_rn(acc2[nf2][j]);
    }
}

// ---------------- SpMM: quarter-partitioned, XCD-pinned (blockIdx%8 heuristic) -----------
// Buffers are [4][n][16ch] bf16 (32-B rows). Block -> xcd = blk&7; quarter = xcd>>1;
// row-half = xcd&1. Wave handles 4 rows; 8-lane group per edge (4 B/lane).
#define ROWS_PW_Q 4

__global__ void spmm_first_q(const int* __restrict__ rowptr, const int2* __restrict__ ecw,
                             const unsigned short* __restrict__ h, unsigned short* __restrict__ tx1,
                             float* __restrict__ accQ, const float* __restrict__ cw,
                             int n, int n2) {
  int blk = blockIdx.x;
  int xcd = blk & 7, rb = blk >> 3;
  int q = xcd >> 1, half = xcd & 1;
  int w = threadIdx.x >> 6, lane = threadIdx.x & 63;
  int lp = lane & 7, g = lane >> 3;
  const unsigned short* qb = h + (size_t)q * n * 16;
  float c0 = cw[0], c1 = cw[1];
#pragma unroll
  for (int rr = 0; rr < ROWS_PW_Q; ++rr) {
    int rl = (rb * 4 + w) * ROWS_PW_Q + rr;
    if (rl >= n2) return;
    int row = half * n2 + rl;
    if (row >= n) return;
    int e0 = rowptr[row], e1 = rowptr[row + 1];
    float s0 = 0.0f, s1 = 0.0f;
    for (int e = e0; e < e1; e += 8) {
      int ee = e + g;
      int ec = (ee < e1) ? ee : (e1 - 1);
      int2 t = ecw[ec];
      unsigned hv = *(const unsigned*)(qb + (((size_t)t.x) << 4) + (lp << 1));
      float wt = (ee < e1) ? __int_as_float(t.y) : 0.0f;
      s0 = fmaf(wt, u2f_lo(hv), s0);
      s1 = fmaf(wt, u2f_hi(hv), s1);
    }
    s0 += __shfl_xor(s0, 8, 64); s0 += __shfl_xor(s0, 16, 64); s0 += __shfl_xor(s0, 32, 64);
    s1 += __shfl_xor(s1, 8, 64); s1 += __shfl_xor(s1, 16, 64); s1 += __shfl_xor(s1, 32, 64);
    if (g == 0) {
      size_t base = ((size_t)q * n + row) * 16 + (lp << 1);
      unsigned hv = *(const unsigned*)(h + base);
      float a0 = c0 * u2f_lo(hv) + c1 * s0;
      float a1 = c0 * u2f_hi(hv) + c1 * s1;
      *(float2*)(accQ + base) = make_float2(a0, a1);
      *(unsigned*)(tx1 + base) = pack2(s0, s1);
    }
  }
}

__global__ void spmm_step_q(const int* __restrict__ rowptr, const int2* __restrict__ ecw,
                            const unsigned short* __restrict__ curb,
                            const unsigned short* __restrict__ prevb,
                            unsigned short* __restrict__ nextb, float* __restrict__ accQ,
                            const float* __restrict__ cw, int k, int last, int n, int n2) {
  int blk = blockIdx.x;
  int xcd = blk & 7, rb = blk >> 3;
  int q = xcd >> 1, half = xcd & 1;
  int w = threadIdx.x >> 6, lane = threadIdx.x & 63;
  int lp = lane & 7, g = lane >> 3;
  const unsigned short* qb = curb + (size_t)q * n * 16;
  float ck = cw[k];
#pragma unroll
  for (int rr = 0; rr < ROWS_PW_Q; ++rr) {
    int rl = (rb * 4 + w) * ROWS_PW_Q + rr;
    if (rl >= n2) return;
    int row = half * n2 + rl;
    if (row >= n) return;
    int e0 = rowptr[row], e1 = rowptr[row + 1];
    float s0 = 0.0f, s1 = 0.0f;
    for (int e = e0; e < e1; e += 8) {
      int ee = e + g;
      int ec = (ee < e1) ? ee : (e1 - 1);
      int2 t = ecw[ec];
      unsigned hv = *(const unsigned*)(qb + (((size_t)t.x) << 4) + (lp << 1));
      float wt = (ee < e1) ? __int_as_float(t.y) : 0.0f;
      s0 = fmaf(wt, u2f_lo(hv), s0);
      s1 = fmaf(wt, u2f_hi(hv), s1);
    }
    s0 += __shfl_xor(s0, 8, 64); s0 += __shfl_xor(s0, 16, 64); s0 += __shfl_xor(s0, 32, 64);
    s1 += __shfl_xor(s1, 8, 64); s1 += __shfl_xor(s1, 16, 64); s1 += __shfl_xor(s1, 32, 64);
    if (g == 0) {
      size_t base = ((size_t)q * n + row) * 16 + (lp << 1);
      unsigned pv = *(const unsigned*)(prevb + base);
      float t0 = 2.0f * s0 - u2f_lo(pv);
      float t1 = 2.0f * s1 - u2f_hi(pv);
      if (!last) *(unsigned*)(nextb + base) = pack2(t0, t1);
      float2 a = *(const float2*)(accQ + base);
      a.x = fmaf(ck, t0, a.x);
      a.y = fmaf(ck, t1, a.y);
      *(float2*)(accQ + base) = a;
    }
  }
}

// ---- final log-softmax: quarter-major fp32 acc -> row-major d_out ----
__global__ void log_softmax_final(const float* __restrict__ accQ, float* __restrict__ out,
                                  int n) {
  int wv = (blockIdx.x * blockDim.x + threadIdx.x) >> 6;
  int ch = threadIdx.x & 63;
  if (wv >= n) return;
  float v = accQ[((size_t)(ch >> 4) * n + wv) * 16 + (ch & 15)];
  float m = v;
#pragma unroll
  for (int off = 32; off > 0; off >>= 1) m = fmaxf(m, __shfl_xor(m, off, 64));
  float ex = expf(v - m);
  float ss = ex;
#pragma unroll
  for (int off = 32; off > 0; off >>= 1) ss += __shfl_xor(ss, off, 64);
  out[(size_t)wv * NCLS + ch] = v - m - logf(ss);
}

// ------------------------- launch -------------------------
extern "C" void kernel_launch(void* const* d_in, const int* in_sizes, int n_in,
                              void* d_out, int out_size, void* d_ws, size_t ws_size,
                              hipStream_t stream) {
  const float* x  = (const float*)d_in[0];
  const int*   ei = (const int*)d_in[1];
  const float* W1 = (const float*)d_in[2];
  const float* W2 = (const float*)d_in[3];
  const float* cw = (const float*)d_in[4];
  float* out = (float*)d_out;

  const int n = in_sizes[0] / NFEAT;     // 100000
  const int E = in_sizes[1] / 2;         // 1600000

  size_t off = 0;
  auto alloc = [&](size_t bytes) { size_t o = off; off += (bytes + 255) & ~(size_t)255; return o; };
  char* w = (char*)d_ws;
  size_t o_cnt   = alloc((size_t)n * 4);
  size_t o_self  = alloc((size_t)n * 4);
  size_t o_cur   = alloc((size_t)n * 4);
  size_t o_dinv  = alloc((size_t)n * 4);      // memset region: o_cnt .. o_dinv
  size_t o_rp    = alloc((size_t)(n + 1) * 4);
  size_t o_bs    = alloc(4096 * 4);
  size_t o_w1fh  = alloc((size_t)KPAD * NHID * 2);
  size_t o_w1fl  = alloc((size_t)KPAD * NHID * 2);
  size_t o_w2f   = alloc((size_t)NHID * NCLS * 2);
  size_t o_ecw   = alloc((size_t)E * 8);
  size_t o_bufH  = alloc((size_t)n * NCLS * 2);
  size_t o_bufA  = alloc((size_t)n * NCLS * 2);
  size_t o_bufB  = alloc((size_t)n * NCLS * 2);
  size_t o_accQ  = alloc((size_t)n * NCLS * 4);

  int*   cnt    = (int*)(w + o_cnt);
  int*   selfc  = (int*)(w + o_self);
  int*   curi   = (int*)(w + o_cur);
  float* dinv   = (float*)(w + o_dinv);
  int*   rowptr = (int*)(w + o_rp);
  int*   bsums  = (int*)(w + o_bs);
  unsigned short* W1Fh = (unsigned short*)(w + o_w1fh);
  unsigned short* W1Fl = (unsigned short*)(w + o_w1fl);
  unsigned short* W2F  = (unsigned short*)(w + o_w2f);
  int2*  ecw    = (int2*)(w + o_ecw);
  unsigned short* bufH = (unsigned short*)(w + o_bufH);
  unsigned short* bufA = (unsigned short*)(w + o_bufA);
  unsigned short* bufB = (unsigned short*)(w + o_bufB);
  float* accQ   = (float*)(w + o_accQ);

  hipMemsetAsync(w + o_cnt, 0, o_dinv - o_cnt, stream);

  const int nb = (n + 255) / 256;

  conv_w1f<<<(KPAD * NHID + 255) / 256, 256, 0, stream>>>(W1, W1Fh, W1Fl);
  conv_w2f<<<(NHID * NCLS + 255) / 256, 256, 0, stream>>>(W2, W2F);

  edge_count<<<1024, 256, 0, stream>>>(ei, E, cnt, selfc);
  make_dinv<<<nb, 256, 0, stream>>>(cnt, selfc, dinv, n);
  scan_block<<<nb, 256, 0, stream>>>(cnt, rowptr, bsums, n);
  scan_sums<<<1, 1, 0, stream>>>(bsums, nb, rowptr);
  scan_add<<<nb, 256, 0, stream>>>(rowptr, bsums, n);
  scatter_edges<<<1024, 256, 0, stream>>>(ei, E, dinv, rowptr, curi, ecw);

  mlp_mfma<<<(n + 63) / 64, 256, 0, stream>>>(x, W1Fh, W1Fl, W2F, bufH, n);

  // quarter-partitioned chain: grid = 8 XCD-slots x BPX row-blocks
  const int n2 = (n + 1) / 2;
  const int BPX = (n2 + 4 * ROWS_PW_Q - 1) / (4 * ROWS_PW_Q);   // waves*rows_pw cover n2
  const int qgrid = 8 * BPX;

  spmm_first_q<<<qgrid, 256, 0, stream>>>(rowptr, ecw, bufH, bufA, accQ, cw, n, n2);

  unsigned short* P = bufH;
  unsigned short* C = bufA;
  unsigned short* N = bufB;
  for (int k = 2; k <= KPOLY; ++k) {
    spmm_step_q<<<qgrid, 256, 0, stream>>>(rowptr, ecw, C, P, N, accQ, cw, k,
                                           (k == KPOLY) ? 1 : 0, n, n2);
    unsigned short* t = P; P = C; C = N; N = t;
  }

  log_softmax_final<<<(n + 3) / 4, 256, 0, stream>>>(accQ, out, n);
}

// Round 13
// 803.447 us; speedup vs baseline: 2.1146x; 2.1146x over previous
//
#include <hip/hip_runtime.h>
#include <hip/hip_bf16.h>
#include <math.h>

#define NFEAT 500
#define KPAD  512
#define NHID  256
#define NCLS  64
#define KPOLY 10

typedef __attribute__((ext_vector_type(8))) short short8;
typedef __attribute__((ext_vector_type(4))) float f32x4;

__device__ inline unsigned short bf16_rn(float v) {
  unsigned u = __float_as_uint(v);
  return (unsigned short)((u + 0x7FFFu + ((u >> 16) & 1u)) >> 16);
}
__device__ inline float u2f_lo(unsigned u) { return __uint_as_float(u << 16); }
__device__ inline float u2f_hi(unsigned u) { return __uint_as_float(u & 0xFFFF0000u); }
__device__ inline unsigned pack2(float a, float b) {
  return (unsigned)bf16_rn(a) | ((unsigned)bf16_rn(b) << 16);
}

// ---------- weight pre-conversion into MFMA fragment layout (bf16 single) ----------
__global__ void conv_w1f(const float* __restrict__ W1, unsigned short* __restrict__ Fh) {
  int i = blockIdx.x * 256 + threadIdx.x;
  if (i >= KPAD * NHID) return;
  int kg = i >> 11, c = (i >> 3) & 255, kin = i & 7;
  int k = kg * 8 + kin;
  float v = (k < NFEAT) ? W1[c * NFEAT + k] : 0.0f;
  Fh[i] = bf16_rn(v);
}
__global__ void conv_w2f(const float* __restrict__ W2, unsigned short* __restrict__ F) {
  int i = blockIdx.x * 256 + threadIdx.x;
  if (i >= NHID * NCLS) return;
  int kg = i >> 9, c = (i >> 3) & 63, kin = i & 7;
  int k = kg * 8 + kin;
  F[i] = bf16_rn(W2[c * NHID + k]);
}

// ------------------------- CSR build -------------------------
__global__ void edge_count(const int* __restrict__ ei, int E,
                           int* __restrict__ cnt, int* __restrict__ selfc) {
  int stride = gridDim.x * blockDim.x;
  for (int e = blockIdx.x * blockDim.x + threadIdx.x; e < E; e += stride) {
    int r = ei[e], c = ei[E + e];
    atomicAdd(&cnt[r], 1);
    if (r == c) atomicAdd(&selfc[r], 1);
  }
}

__global__ void make_dinv(const int* __restrict__ cnt, const int* __restrict__ selfc,
                          float* __restrict__ dinv, int n) {
  int i = blockIdx.x * blockDim.x + threadIdx.x;
  if (i < n) {
    int d = cnt[i] - selfc[i];
    dinv[i] = (d > 0) ? rsqrtf((float)d) : 0.0f;
  }
}

__global__ void scan_block(const int* __restrict__ cnt, int* __restrict__ rowptr,
                           int* __restrict__ bsums, int n) {
  __shared__ int s[256];
  int i = blockIdx.x * 256 + threadIdx.x;
  int v = (i < n) ? cnt[i] : 0;
  s[threadIdx.x] = v;
  __syncthreads();
  for (int off = 1; off < 256; off <<= 1) {
    int t = (threadIdx.x >= (unsigned)off) ? s[threadIdx.x - off] : 0;
    __syncthreads();
    s[threadIdx.x] += t;
    __syncthreads();
  }
  if (i < n) rowptr[i + 1] = s[threadIdx.x];
  if (threadIdx.x == 255) bsums[blockIdx.x] = s[255];
}

__global__ void scan_sums(int* __restrict__ bsums, int nb, int* __restrict__ rowptr) {
  if (threadIdx.x == 0 && blockIdx.x == 0) {
    int run = 0;
    for (int b = 0; b < nb; ++b) { int t = bsums[b]; bsums[b] = run; run += t; }
    rowptr[0] = 0;
  }
}

__global__ void scan_add(int* __restrict__ rowptr, const int* __restrict__ bsums, int n) {
  int i = blockIdx.x * 256 + threadIdx.x;
  if (i < n) rowptr[i + 1] += bsums[i >> 8];
}

__global__ void scatter_edges(const int* __restrict__ ei, int E,
                              const float* __restrict__ dinv,
                              const int* __restrict__ rowptr, int* __restrict__ cur,
                              int2* __restrict__ ecw) {
  int stride = gridDim.x * blockDim.x;
  for (int e = blockIdx.x * blockDim.x + threadIdx.x; e < E; e += stride) {
    int r = ei[e], c = ei[E + e];
    int pos = rowptr[r] + atomicAdd(&cur[r], 1);
    float wt = (r != c) ? (-dinv[r] * dinv[c]) : 0.0f;
    ecw[pos] = make_int2(c, __float_as_int(wt));
  }
}

// ------------------------- fused MLP via MFMA (all-bf16) -------------------------
// Persistent grid (each block loops tiles), pipelined A staging (double-buffered
// LDS, 1 barrier/K-step), B frags direct from global (L2-resident).
__global__ __launch_bounds__(256, 4) void mlp_mfma(
    const float* __restrict__ x, const unsigned short* __restrict__ W1F,
    const unsigned short* __restrict__ W2F, unsigned short* __restrict__ hout,
    int n, int ntiles)
{
  __shared__ union {
    struct { unsigned short A[2][4][64][8]; } g1;   // 8 KB (double-buffered A tile)
    struct { unsigned short A2[32][64][8]; } g2;    // 32 KB (relu(h) frags)
  } u;

  const int tid = threadIdx.x;
  const int w = tid >> 6;
  const int l = tid & 63;
  const int l15 = l & 15, l4 = l >> 4;
  const f32x4 zf = {0.0f, 0.0f, 0.0f, 0.0f};

  for (int tile = blockIdx.x; tile < ntiles; tile += gridDim.x) {
    const int row0 = tile * 64;

    f32x4 acc[4][4];
#pragma unroll
    for (int i = 0; i < 4; ++i)
#pragma unroll
      for (int j = 0; j < 4; ++j) acc[i][j] = zf;

    // prologue: stage tile 0 into buffer 0
#pragma unroll
    for (int s = 0; s < 2; ++s) {
      int f = tid + s * 256;
      int r = f >> 3, slot = f & 7;
      int gr = row0 + r, gk = slot * 4;
      float4 v = make_float4(0.f, 0.f, 0.f, 0.f);
      if (gr < n && gk + 3 < NFEAT)
        v = *(const float4*)&x[(size_t)gr * NFEAT + gk];
      int kg = slot >> 1, kin0 = (slot & 1) * 4;
      *(uint2*)&u.g1.A[0][kg][r][kin0] = make_uint2(pack2(v.x, v.y), pack2(v.z, v.w));
    }
    __syncthreads();

    for (int t = 0; t < 16; ++t) {
      const int cur = t & 1;
      // 1) prefetch next x tile to registers
      float4 va[2];
      if (t < 15) {
#pragma unroll
        for (int s = 0; s < 2; ++s) {
          int f = tid + s * 256;
          int r = f >> 3, slot = f & 7;
          int gr = row0 + r, gk = (t + 1) * 32 + slot * 4;
          va[s] = make_float4(0.f, 0.f, 0.f, 0.f);
          if (gr < n && gk + 3 < NFEAT)
            va[s] = *(const float4*)&x[(size_t)gr * NFEAT + gk];
        }
      }
      // 2) B fragments for this step (global, L2-resident)
      short8 bH[4];
#pragma unroll
      for (int nf = 0; nf < 4; ++nf) {
        size_t bi = (size_t)t * 8192 + ((size_t)l4 * 256 + w * 64 + nf * 16 + l15) * 8;
        bH[nf] = *(const short8*)(W1F + bi);
      }
      // 3) MFMAs on buffer `cur`
#pragma unroll
      for (int mf = 0; mf < 4; ++mf) {
        short8 aH = *(const short8*)&u.g1.A[cur][l4][mf * 16 + l15][0];
#pragma unroll
        for (int nf = 0; nf < 4; ++nf)
          acc[mf][nf] = __builtin_amdgcn_mfma_f32_16x16x32_bf16(aH, bH[nf], acc[mf][nf], 0, 0, 0);
      }
      // 4) write prefetched tile into the other buffer
      if (t < 15) {
#pragma unroll
        for (int s = 0; s < 2; ++s) {
          int f = tid + s * 256;
          int r = f >> 3, slot = f & 7;
          int kg = slot >> 1, kin0 = (slot & 1) * 4;
          *(uint2*)&u.g1.A[cur ^ 1][kg][r][kin0] =
              make_uint2(pack2(va[s].x, va[s].y), pack2(va[s].z, va[s].w));
        }
      }
      __syncthreads();
    }

    // ---- exchange relu(h) as bf16 A2 frags ----
#pragma unroll
    for (int mf = 0; mf < 4; ++mf)
#pragma unroll
      for (int nf = 0; nf < 4; ++nf) {
        int col = w * 64 + nf * 16 + l15;
        int kg = col >> 3, kin = col & 7;
#pragma unroll
        for (int j = 0; j < 4; ++j) {
          float vv = fmaxf(acc[mf][nf][j], 0.0f);
          u.g2.A2[kg][mf * 16 + l4 * 4 + j][kin] = bf16_rn(vv);
        }
      }
    __syncthreads();

    // ---- GEMM2 ----
    f32x4 acc2[4];
#pragma unroll
    for (int i = 0; i < 4; ++i) acc2[i] = zf;
#pragma unroll
    for (int ks = 0; ks < 8; ++ks) {
      short8 a2 = *(const short8*)&u.g2.A2[ks * 4 + l4][w * 16 + l15][0];
#pragma unroll
      for (int nf2 = 0; nf2 < 4; ++nf2) {
        size_t bi = ((size_t)(ks * 4 + l4) * 64 + nf2 * 16 + l15) * 8;
        short8 b2 = *(const short8*)(W2F + bi);
        acc2[nf2] = __builtin_amdgcn_mfma_f32_16x16x32_bf16(a2, b2, acc2[nf2], 0, 0, 0);
      }
    }
#pragma unroll
    for (int nf2 = 0; nf2 < 4; ++nf2)
#pragma unroll
      for (int j = 0; j < 4; ++j) {
        int r = row0 + w * 16 + l4 * 4 + j;
        if (r < n) hout[(size_t)r * NCLS + nf2 * 16 + l15] = bf16_rn(acc2[nf2][j]);
      }
    __syncthreads();   // protect LDS union before next tile's staging
  }
}

// ---------------- SpMM: 2 rows per wave, 8 lanes/edge (round-10 proven) --------
__device__ inline void acc8(float s[8], float w, uint4 h) {
  s[0] = fmaf(w, u2f_lo(h.x), s[0]); s[1] = fmaf(w, u2f_hi(h.x), s[1]);
  s[2] = fmaf(w, u2f_lo(h.y), s[2]); s[3] = fmaf(w, u2f_hi(h.y), s[3]);
  s[4] = fmaf(w, u2f_lo(h.z), s[4]); s[5] = fmaf(w, u2f_hi(h.z), s[5]);
  s[6] = fmaf(w, u2f_lo(h.w), s[6]); s[7] = fmaf(w, u2f_hi(h.w), s[7]);
}

__device__ inline void gather_two(const int* __restrict__ rowptr,
                                  const int2* __restrict__ ecw,
                                  const unsigned short* __restrict__ src,
                                  int rowA, int rowB, bool hasB, int p, int g,
                                  float sA[8], float sB[8]) {
#pragma unroll
  for (int i = 0; i < 8; ++i) { sA[i] = 0.0f; sB[i] = 0.0f; }
  int e0a = rowptr[rowA], e1a = rowptr[rowA + 1];
  int e0b = 0, e1b = 0;
  if (hasB) { e0b = rowptr[rowB]; e1b = rowptr[rowB + 1]; }
  int ita = (e1a - e0a + 15) >> 4;
  int itb = (e1b - e0b + 15) >> 4;
  int itm = (ita > itb) ? ita : itb;
  const unsigned short* bp = src + (p << 3);
  for (int it = 0; it < itm; ++it) {
    int ba = e0a + it * 16, bb = e0b + it * 16;
    int eeA0 = ba + g,     eeA1 = ba + 8 + g;
    int eeB0 = bb + g,     eeB1 = bb + 8 + g;
    int iA0 = max(min(eeA0, e1a - 1), 0);
    int iA1 = max(min(eeA1, e1a - 1), 0);
    int iB0 = max(min(eeB0, e1b - 1), 0);
    int iB1 = max(min(eeB1, e1b - 1), 0);
    int2 tA0 = ecw[iA0];
    int2 tA1 = ecw[iA1];
    int2 tB0 = ecw[iB0];
    int2 tB1 = ecw[iB1];
    uint4 hA0 = *(const uint4*)(bp + (((size_t)tA0.x) << 6));
    uint4 hA1 = *(const uint4*)(bp + (((size_t)tA1.x) << 6));
    uint4 hB0 = *(const uint4*)(bp + (((size_t)tB0.x) << 6));
    uint4 hB1 = *(const uint4*)(bp + (((size_t)tB1.x) << 6));
    float wA0 = (eeA0 < e1a) ? __int_as_float(tA0.y) : 0.0f;
    float wA1 = (eeA1 < e1a) ? __int_as_float(tA1.y) : 0.0f;
    float wB0 = (eeB0 < e1b) ? __int_as_float(tB0.y) : 0.0f;
    float wB1 = (eeB1 < e1b) ? __int_as_float(tB1.y) : 0.0f;
    acc8(sA, wA0, hA0);
    acc8(sA, wA1, hA1);
    acc8(sB, wB0, hB0);
    acc8(sB, wB1, hB1);
  }
#pragma unroll
  for (int i = 0; i < 8; ++i) {
    sA[i] += __shfl_xor(sA[i], 8, 64);
    sA[i] += __shfl_xor(sA[i], 16, 64);
    sA[i] += __shfl_xor(sA[i], 32, 64);
    sB[i] += __shfl_xor(sB[i], 8, 64);
    sB[i] += __shfl_xor(sB[i], 16, 64);
    sB[i] += __shfl_xor(sB[i], 32, 64);
  }
}

__device__ inline void first_epilogue(const unsigned short* __restrict__ h,
                                      unsigned short* __restrict__ tx1,
                                      float* __restrict__ acc, float c0, float c1,
                                      size_t base, const float s[8]) {
  uint4 hv = *(const uint4*)(h + base);
  float4 a0, a1;
  a0.x = c0 * u2f_lo(hv.x) + c1 * s[0]; a0.y = c0 * u2f_hi(hv.x) + c1 * s[1];
  a0.z = c0 * u2f_lo(hv.y) + c1 * s[2]; a0.w = c0 * u2f_hi(hv.y) + c1 * s[3];
  a1.x = c0 * u2f_lo(hv.z) + c1 * s[4]; a1.y = c0 * u2f_hi(hv.z) + c1 * s[5];
  a1.z = c0 * u2f_lo(hv.w) + c1 * s[6]; a1.w = c0 * u2f_hi(hv.w) + c1 * s[7];
  *(float4*)(acc + base) = a0;
  *(float4*)(acc + base + 4) = a1;
  uint4 tw;
  tw.x = pack2(s[0], s[1]); tw.y = pack2(s[2], s[3]);
  tw.z = pack2(s[4], s[5]); tw.w = pack2(s[6], s[7]);
  *(uint4*)(tx1 + base) = tw;
}

__global__ void spmm_first(const int* __restrict__ rowptr, const int2* __restrict__ ecw,
                           const unsigned short* __restrict__ h, unsigned short* __restrict__ tx1,
                           float* __restrict__ acc, const float* __restrict__ cw, int n) {
  int wv = (blockIdx.x * blockDim.x + threadIdx.x) >> 6;
  int lane = threadIdx.x & 63;
  int p = lane & 7, g = lane >> 3;
  int rowA = wv * 2;
  if (rowA >= n) return;
  int rowB = rowA + 1;
  bool hasB = rowB < n;
  float sA[8], sB[8];
  gather_two(rowptr, ecw, h, rowA, hasB ? rowB : rowA, hasB, p, g, sA, sB);
  float c0 = cw[0], c1 = cw[1];
  if (g == 0)
    first_epilogue(h, tx1, acc, c0, c1, (size_t)rowA * NCLS + (p << 3), sA);
  if (g == 1 && hasB)
    first_epilogue(h, tx1, acc, c0, c1, (size_t)rowB * NCLS + (p << 3), sB);
}

__device__ inline void step_epilogue(const unsigned short* __restrict__ prevb,
                                     unsigned short* __restrict__ nextb,
                                     float* __restrict__ acc, float ck, int last,
                                     size_t base, const float s[8]) {
  uint4 pv = *(const uint4*)(prevb + base);
  float t[8];
  t[0] = 2.0f * s[0] - u2f_lo(pv.x); t[1] = 2.0f * s[1] - u2f_hi(pv.x);
  t[2] = 2.0f * s[2] - u2f_lo(pv.y); t[3] = 2.0f * s[3] - u2f_hi(pv.y);
  t[4] = 2.0f * s[4] - u2f_lo(pv.z); t[5] = 2.0f * s[5] - u2f_hi(pv.z);
  t[6] = 2.0f * s[6] - u2f_lo(pv.w); t[7] = 2.0f * s[7] - u2f_hi(pv.w);
  if (!last) {
    uint4 nw;
    nw.x = pack2(t[0], t[1]); nw.y = pack2(t[2], t[3]);
    nw.z = pack2(t[4], t[5]); nw.w = pack2(t[6], t[7]);
    *(uint4*)(nextb + base) = nw;
    float4 a0 = *(const float4*)(acc + base);
    float4 a1 = *(const float4*)(acc + base + 4);
    a0.x = fmaf(ck, t[0], a0.x); a0.y = fmaf(ck, t[1], a0.y);
    a0.z = fmaf(ck, t[2], a0.z); a0.w = fmaf(ck, t[3], a0.w);
    a1.x = fmaf(ck, t[4], a1.x); a1.y = fmaf(ck, t[5], a1.y);
    a1.z = fmaf(ck, t[6], a1.z); a1.w = fmaf(ck, t[7], a1.w);
    *(float4*)(acc + base) = a0;
    *(float4*)(acc + base + 4) = a1;
  } else {
    float4 a0 = *(const float4*)(acc + base);
    float4 a1 = *(const float4*)(acc + base + 4);
    float v[8];
    v[0] = fmaf(ck, t[0], a0.x); v[1] = fmaf(ck, t[1], a0.y);
    v[2] = fmaf(ck, t[2], a0.z); v[3] = fmaf(ck, t[3], a0.w);
    v[4] = fmaf(ck, t[4], a1.x); v[5] = fmaf(ck, t[5], a1.y);
    v[6] = fmaf(ck, t[6], a1.z); v[7] = fmaf(ck, t[7], a1.w);
    float m = v[0];
#pragma unroll
    for (int i = 1; i < 8; ++i) m = fmaxf(m, v[i]);
    m = fmaxf(m, __shfl_xor(m, 1, 64));
    m = fmaxf(m, __shfl_xor(m, 2, 64));
    m = fmaxf(m, __shfl_xor(m, 4, 64));
    float ss = 0.0f;
#pragma unroll
    for (int i = 0; i < 8; ++i) ss += expf(v[i] - m);
    ss += __shfl_xor(ss, 1, 64);
    ss += __shfl_xor(ss, 2, 64);
    ss += __shfl_xor(ss, 4, 64);
    float lg = m + logf(ss);
    float4 o0, o1;
    o0.x = v[0] - lg; o0.y = v[1] - lg; o0.z = v[2] - lg; o0.w = v[3] - lg;
    o1.x = v[4] - lg; o1.y = v[5] - lg; o1.z = v[6] - lg; o1.w = v[7] - lg;
    *(float4*)(acc + base) = o0;
    *(float4*)(acc + base + 4) = o1;
  }
}

__global__ void spmm_step(const int* __restrict__ rowptr, const int2* __restrict__ ecw,
                          const unsigned short* __restrict__ curb,
                          const unsigned short* __restrict__ prevb,
                          unsigned short* __restrict__ nextb, float* __restrict__ acc,
                          const float* __restrict__ cw, int k, int last, int n) {
  int wv = (blockIdx.x * blockDim.x + threadIdx.x) >> 6;
  int lane = threadIdx.x & 63;
  int p = lane & 7, g = lane >> 3;
  int rowA = wv * 2;
  if (rowA >= n) return;
  int rowB = rowA + 1;
  bool hasB = rowB < n;
  float sA[8], sB[8];
  gather_two(rowptr, ecw, curb, rowA, hasB ? rowB : rowA, hasB, p, g, sA, sB);
  float ck = cw[k];
  if (g == 0)
    step_epilogue(prevb, nextb, acc, ck, last, (size_t)rowA * NCLS + (p << 3), sA);
  if (g == 1 && hasB)
    step_epilogue(prevb, nextb, acc, ck, last, (size_t)rowB * NCLS + (p << 3), sB);
}

// ------------------------- launch -------------------------
extern "C" void kernel_launch(void* const* d_in, const int* in_sizes, int n_in,
                              void* d_out, int out_size, void* d_ws, size_t ws_size,
                              hipStream_t stream) {
  const float* x  = (const float*)d_in[0];
  const int*   ei = (const int*)d_in[1];
  const float* W1 = (const float*)d_in[2];
  const float* W2 = (const float*)d_in[3];
  const float* cw = (const float*)d_in[4];
  float* out = (float*)d_out;

  const int n = in_sizes[0] / NFEAT;     // 100000
  const int E = in_sizes[1] / 2;         // 1600000

  size_t off = 0;
  auto alloc = [&](size_t bytes) { size_t o = off; off += (bytes + 255) & ~(size_t)255; return o; };
  char* w = (char*)d_ws;
  size_t o_cnt   = alloc((size_t)n * 4);
  size_t o_self  = alloc((size_t)n * 4);
  size_t o_cur   = alloc((size_t)n * 4);
  size_t o_dinv  = alloc((size_t)n * 4);      // memset region: o_cnt .. o_dinv
  size_t o_rp    = alloc((size_t)(n + 1) * 4);
  size_t o_bs    = alloc(4096 * 4);
  size_t o_w1f   = alloc((size_t)KPAD * NHID * 2);
  size_t o_w2f   = alloc((size_t)NHID * NCLS * 2);
  size_t o_ecw   = alloc((size_t)E * 8);
  size_t o_bufH  = alloc((size_t)n * NCLS * 2);
  size_t o_bufA  = alloc((size_t)n * NCLS * 2);
  size_t o_bufB  = alloc((size_t)n * NCLS * 2);

  int*   cnt    = (int*)(w + o_cnt);
  int*   selfc  = (int*)(w + o_self);
  int*   curi   = (int*)(w + o_cur);
  float* dinv   = (float*)(w + o_dinv);
  int*   rowptr = (int*)(w + o_rp);
  int*   bsums  = (int*)(w + o_bs);
  unsigned short* W1F = (unsigned short*)(w + o_w1f);
  unsigned short* W2F = (unsigned short*)(w + o_w2f);
  int2*  ecw    = (int2*)(w + o_ecw);
  unsigned short* bufH = (unsigned short*)(w + o_bufH);
  unsigned short* bufA = (unsigned short*)(w + o_bufA);
  unsigned short* bufB = (unsigned short*)(w + o_bufB);

  hipMemsetAsync(w + o_cnt, 0, o_dinv - o_cnt, stream);

  const int nb = (n + 255) / 256;

  conv_w1f<<<(KPAD * NHID + 255) / 256, 256, 0, stream>>>(W1, W1F);
  conv_w2f<<<(NHID * NCLS + 255) / 256, 256, 0, stream>>>(W2, W2F);

  edge_count<<<1024, 256, 0, stream>>>(ei, E, cnt, selfc);
  make_dinv<<<nb, 256, 0, stream>>>(cnt, selfc, dinv, n);
  scan_block<<<nb, 256, 0, stream>>>(cnt, rowptr, bsums, n);
  scan_sums<<<1, 1, 0, stream>>>(bsums, nb, rowptr);
  scan_add<<<nb, 256, 0, stream>>>(rowptr, bsums, n);
  scatter_edges<<<1024, 256, 0, stream>>>(ei, E, dinv, rowptr, curi, ecw);

  // persistent balanced grid: 782 blocks, each handles 2 tiles (1563 tiles total)
  const int ntiles = (n + 63) / 64;
  const int mlp_grid = (ntiles + 1) / 2;
  mlp_mfma<<<mlp_grid, 256, 0, stream>>>(x, W1F, W2F, bufH, n, ntiles);

  // 2 rows per wave, 4 waves per block
  const int waves = (n + 1) / 2;
  const int spmm_blocks = (waves + 3) / 4;
  spmm_first<<<spmm_blocks, 256, 0, stream>>>(rowptr, ecw, bufH, bufA, out, cw, n);

  unsigned short* P = bufH;
  unsigned short* C = bufA;
  unsigned short* N = bufB;
  for (int k = 2; k <= KPOLY; ++k) {
    spmm_step<<<spmm_blocks, 256, 0, stream>>>(rowptr, ecw, C, P, N, out, cw, k,
                                               (k == KPOLY) ? 1 : 0, n);
    unsigned short* t = P; P = C; C = N; N = t;
  }
}

// Round 14
// 727.851 us; speedup vs baseline: 2.3342x; 1.1039x over previous
//
#include <hip/hip_runtime.h>
#include <hip/hip_bf16.h>
#include <math.h>

#define NFEAT 500
#define KPAD  512
#define NHID  256
#define NCLS  64
#define KPOLY 10

typedef __attribute__((ext_vector_type(8))) short short8;
typedef __attribute__((ext_vector_type(4))) float f32x4;

__device__ inline unsigned short bf16_rn(float v) {
  unsigned u = __float_as_uint(v);
  return (unsigned short)((u + 0x7FFFu + ((u >> 16) & 1u)) >> 16);
}
__device__ inline float u2f_lo(unsigned u) { return __uint_as_float(u << 16); }
__device__ inline float u2f_hi(unsigned u) { return __uint_as_float(u & 0xFFFF0000u); }
__device__ inline unsigned pack2(float a, float b) {
  return (unsigned)bf16_rn(a) | ((unsigned)bf16_rn(b) << 16);
}

// ---------- weight pre-conversion into MFMA fragment layout (bf16 single) ----------
__global__ void conv_w1f(const float* __restrict__ W1, unsigned short* __restrict__ Fh) {
  int i = blockIdx.x * 256 + threadIdx.x;
  if (i >= KPAD * NHID) return;
  int kg = i >> 11, c = (i >> 3) & 255, kin = i & 7;
  int k = kg * 8 + kin;
  float v = (k < NFEAT) ? W1[c * NFEAT + k] : 0.0f;
  Fh[i] = bf16_rn(v);
}
__global__ void conv_w2f(const float* __restrict__ W2, unsigned short* __restrict__ F) {
  int i = blockIdx.x * 256 + threadIdx.x;
  if (i >= NHID * NCLS) return;
  int kg = i >> 9, c = (i >> 3) & 63, kin = i & 7;
  int k = kg * 8 + kin;
  F[i] = bf16_rn(W2[c * NHID + k]);
}

// ------------------------- CSR build -------------------------
__global__ void edge_count(const int* __restrict__ ei, int E,
                           int* __restrict__ cnt, int* __restrict__ selfc) {
  int stride = gridDim.x * blockDim.x;
  for (int e = blockIdx.x * blockDim.x + threadIdx.x; e < E; e += stride) {
    int r = ei[e], c = ei[E + e];
    atomicAdd(&cnt[r], 1);
    if (r == c) atomicAdd(&selfc[r], 1);
  }
}

__global__ void make_dinv(const int* __restrict__ cnt, const int* __restrict__ selfc,
                          float* __restrict__ dinv, int n) {
  int i = blockIdx.x * blockDim.x + threadIdx.x;
  if (i < n) {
    int d = cnt[i] - selfc[i];
    dinv[i] = (d > 0) ? rsqrtf((float)d) : 0.0f;
  }
}

__global__ void scan_block(const int* __restrict__ cnt, int* __restrict__ rowptr,
                           int* __restrict__ bsums, int n) {
  __shared__ int s[256];
  int i = blockIdx.x * 256 + threadIdx.x;
  int v = (i < n) ? cnt[i] : 0;
  s[threadIdx.x] = v;
  __syncthreads();
  for (int off = 1; off < 256; off <<= 1) {
    int t = (threadIdx.x >= (unsigned)off) ? s[threadIdx.x - off] : 0;
    __syncthreads();
    s[threadIdx.x] += t;
    __syncthreads();
  }
  if (i < n) rowptr[i + 1] = s[threadIdx.x];
  if (threadIdx.x == 255) bsums[blockIdx.x] = s[255];
}

__global__ void scan_sums(int* __restrict__ bsums, int nb, int* __restrict__ rowptr) {
  if (threadIdx.x == 0 && blockIdx.x == 0) {
    int run = 0;
    for (int b = 0; b < nb; ++b) { int t = bsums[b]; bsums[b] = run; run += t; }
    rowptr[0] = 0;
  }
}

__global__ void scan_add(int* __restrict__ rowptr, const int* __restrict__ bsums, int n) {
  int i = blockIdx.x * 256 + threadIdx.x;
  if (i < n) rowptr[i + 1] += bsums[i >> 8];
}

__global__ void scatter_edges(const int* __restrict__ ei, int E,
                              const float* __restrict__ dinv,
                              const int* __restrict__ rowptr, int* __restrict__ cur,
                              int2* __restrict__ ecw) {
  int stride = gridDim.x * blockDim.x;
  for (int e = blockIdx.x * blockDim.x + threadIdx.x; e < E; e += stride) {
    int r = ei[e], c = ei[E + e];
    int pos = rowptr[r] + atomicAdd(&cur[r], 1);
    float wt = (r != c) ? (-dinv[r] * dinv[c]) : 0.0f;
    ecw[pos] = make_int2(c, __float_as_int(wt));
  }
}

// ------------------------- fused MLP via MFMA (all-bf16, non-persistent) ------------------
// One 64-row tile per block. Double-buffered A staging in LDS, 1 barrier/K-step,
// B fragments direct from global (L2-resident).
__global__ __launch_bounds__(256, 4) void mlp_mfma(
    const float* __restrict__ x, const unsigned short* __restrict__ W1F,
    const unsigned short* __restrict__ W2F, unsigned short* __restrict__ hout, int n)
{
  __shared__ union {
    struct { unsigned short A[2][4][64][8]; } g1;   // 8 KB (double-buffered A tile)
    struct { unsigned short A2[32][64][8]; } g2;    // 32 KB (relu(h) frags)
  } u;

  const int tid = threadIdx.x;
  const int w = tid >> 6;
  const int l = tid & 63;
  const int l15 = l & 15, l4 = l >> 4;
  const int row0 = blockIdx.x * 64;
  const f32x4 zf = {0.0f, 0.0f, 0.0f, 0.0f};

  f32x4 acc[4][4];
#pragma unroll
  for (int i = 0; i < 4; ++i)
#pragma unroll
    for (int j = 0; j < 4; ++j) acc[i][j] = zf;

  // prologue: stage tile 0 into buffer 0
#pragma unroll
  for (int s = 0; s < 2; ++s) {
    int f = tid + s * 256;
    int r = f >> 3, slot = f & 7;
    int gr = row0 + r, gk = slot * 4;
    float4 v = make_float4(0.f, 0.f, 0.f, 0.f);
    if (gr < n && gk + 3 < NFEAT)
      v = *(const float4*)&x[(size_t)gr * NFEAT + gk];
    int kg = slot >> 1, kin0 = (slot & 1) * 4;
    *(uint2*)&u.g1.A[0][kg][r][kin0] = make_uint2(pack2(v.x, v.y), pack2(v.z, v.w));
  }
  __syncthreads();

  for (int t = 0; t < 16; ++t) {
    const int cur = t & 1;
    // 1) prefetch next x tile to registers
    float4 va[2];
    if (t < 15) {
#pragma unroll
      for (int s = 0; s < 2; ++s) {
        int f = tid + s * 256;
        int r = f >> 3, slot = f & 7;
        int gr = row0 + r, gk = (t + 1) * 32 + slot * 4;
        va[s] = make_float4(0.f, 0.f, 0.f, 0.f);
        if (gr < n && gk + 3 < NFEAT)
          va[s] = *(const float4*)&x[(size_t)gr * NFEAT + gk];
      }
    }
    // 2) B fragments for this step
    short8 bH[4];
#pragma unroll
    for (int nf = 0; nf < 4; ++nf) {
      size_t bi = (size_t)t * 8192 + ((size_t)l4 * 256 + w * 64 + nf * 16 + l15) * 8;
      bH[nf] = *(const short8*)(W1F + bi);
    }
    // 3) MFMAs on buffer `cur`
#pragma unroll
    for (int mf = 0; mf < 4; ++mf) {
      short8 aH = *(const short8*)&u.g1.A[cur][l4][mf * 16 + l15][0];
#pragma unroll
      for (int nf = 0; nf < 4; ++nf)
        acc[mf][nf] = __builtin_amdgcn_mfma_f32_16x16x32_bf16(aH, bH[nf], acc[mf][nf], 0, 0, 0);
    }
    // 4) write prefetched tile into the other buffer
    if (t < 15) {
#pragma unroll
      for (int s = 0; s < 2; ++s) {
        int f = tid + s * 256;
        int r = f >> 3, slot = f & 7;
        int kg = slot >> 1, kin0 = (slot & 1) * 4;
        *(uint2*)&u.g1.A[cur ^ 1][kg][r][kin0] =
            make_uint2(pack2(va[s].x, va[s].y), pack2(va[s].z, va[s].w));
      }
    }
    __syncthreads();
  }

  // ---- exchange relu(h) as bf16 A2 frags ----
#pragma unroll
  for (int mf = 0; mf < 4; ++mf)
#pragma unroll
    for (int nf = 0; nf < 4; ++nf) {
      int col = w * 64 + nf * 16 + l15;
      int kg = col >> 3, kin = col & 7;
#pragma unroll
      for (int j = 0; j < 4; ++j) {
        float vv = fmaxf(acc[mf][nf][j], 0.0f);
        u.g2.A2[kg][mf * 16 + l4 * 4 + j][kin] = bf16_rn(vv);
      }
    }
  __syncthreads();

  // ---- GEMM2 ----
  f32x4 acc2[4];
#pragma unroll
  for (int i = 0; i < 4; ++i) acc2[i] = zf;
#pragma unroll
  for (int ks = 0; ks < 8; ++ks) {
    short8 a2 = *(const short8*)&u.g2.A2[ks * 4 + l4][w * 16 + l15][0];
#pragma unroll
    for (int nf2 = 0; nf2 < 4; ++nf2) {
      size_t bi = ((size_t)(ks * 4 + l4) * 64 + nf2 * 16 + l15) * 8;
      short8 b2 = *(const short8*)(W2F + bi);
      acc2[nf2] = __builtin_amdgcn_mfma_f32_16x16x32_bf16(a2, b2, acc2[nf2], 0, 0, 0);
    }
  }
#pragma unroll
  for (int nf2 = 0; nf2 < 4; ++nf2)
#pragma unroll
    for (int j = 0; j < 4; ++j) {
      int r = row0 + w * 16 + l4 * 4 + j;
      if (r < n) hout[(size_t)r * NCLS + nf2 * 16 + l15] = bf16_rn(acc2[nf2][j]);
    }
}

// ---------------- SpMM: 2 rows per wave, 8 lanes/edge (round-10 proven) --------
__device__ inline void acc8(float s[8], float w, uint4 h) {
  s[0] = fmaf(w, u2f_lo(h.x), s[0]); s[1] = fmaf(w, u2f_hi(h.x), s[1]);
  s[2] = fmaf(w, u2f_lo(h.y), s[2]); s[3] = fmaf(w, u2f_hi(h.y), s[3]);
  s[4] = fmaf(w, u2f_lo(h.z), s[4]); s[5] = fmaf(w, u2f_hi(h.z), s[5]);
  s[6] = fmaf(w, u2f_lo(h.w), s[6]); s[7] = fmaf(w, u2f_hi(h.w), s[7]);
}

__device__ inline void gather_two(const int* __restrict__ rowptr,
                                  const int2* __restrict__ ecw,
                                  const unsigned short* __restrict__ src,
                                  int rowA, int rowB, bool hasB, int p, int g,
                                  float sA[8], float sB[8]) {
#pragma unroll
  for (int i = 0; i < 8; ++i) { sA[i] = 0.0f; sB[i] = 0.0f; }
  int e0a = rowptr[rowA], e1a = rowptr[rowA + 1];
  int e0b = 0, e1b = 0;
  if (hasB) { e0b = rowptr[rowB]; e1b = rowptr[rowB + 1]; }
  int ita = (e1a - e0a + 15) >> 4;
  int itb = (e1b - e0b + 15) >> 4;
  int itm = (ita > itb) ? ita : itb;
  const unsigned short* bp = src + (p << 3);
  for (int it = 0; it < itm; ++it) {
    int ba = e0a + it * 16, bb = e0b + it * 16;
    int eeA0 = ba + g,     eeA1 = ba + 8 + g;
    int eeB0 = bb + g,     eeB1 = bb + 8 + g;
    int iA0 = max(min(eeA0, e1a - 1), 0);
    int iA1 = max(min(eeA1, e1a - 1), 0);
    int iB0 = max(min(eeB0, e1b - 1), 0);
    int iB1 = max(min(eeB1, e1b - 1), 0);
    int2 tA0 = ecw[iA0];
    int2 tA1 = ecw[iA1];
    int2 tB0 = ecw[iB0];
    int2 tB1 = ecw[iB1];
    uint4 hA0 = *(const uint4*)(bp + (((size_t)tA0.x) << 6));
    uint4 hA1 = *(const uint4*)(bp + (((size_t)tA1.x) << 6));
    uint4 hB0 = *(const uint4*)(bp + (((size_t)tB0.x) << 6));
    uint4 hB1 = *(const uint4*)(bp + (((size_t)tB1.x) << 6));
    float wA0 = (eeA0 < e1a) ? __int_as_float(tA0.y) : 0.0f;
    float wA1 = (eeA1 < e1a) ? __int_as_float(tA1.y) : 0.0f;
    float wB0 = (eeB0 < e1b) ? __int_as_float(tB0.y) : 0.0f;
    float wB1 = (eeB1 < e1b) ? __int_as_float(tB1.y) : 0.0f;
    acc8(sA, wA0, hA0);
    acc8(sA, wA1, hA1);
    acc8(sB, wB0, hB0);
    acc8(sB, wB1, hB1);
  }
#pragma unroll
  for (int i = 0; i < 8; ++i) {
    sA[i] += __shfl_xor(sA[i], 8, 64);
    sA[i] += __shfl_xor(sA[i], 16, 64);
    sA[i] += __shfl_xor(sA[i], 32, 64);
    sB[i] += __shfl_xor(sB[i], 8, 64);
    sB[i] += __shfl_xor(sB[i], 16, 64);
    sB[i] += __shfl_xor(sB[i], 32, 64);
  }
}

__device__ inline void first_epilogue(const unsigned short* __restrict__ h,
                                      unsigned short* __restrict__ tx1,
                                      float* __restrict__ acc, float c0, float c1,
                                      size_t base, const float s[8]) {
  uint4 hv = *(const uint4*)(h + base);
  float4 a0, a1;
  a0.x = c0 * u2f_lo(hv.x) + c1 * s[0]; a0.y = c0 * u2f_hi(hv.x) + c1 * s[1];
  a0.z = c0 * u2f_lo(hv.y) + c1 * s[2]; a0.w = c0 * u2f_hi(hv.y) + c1 * s[3];
  a1.x = c0 * u2f_lo(hv.z) + c1 * s[4]; a1.y = c0 * u2f_hi(hv.z) + c1 * s[5];
  a1.z = c0 * u2f_lo(hv.w) + c1 * s[6]; a1.w = c0 * u2f_hi(hv.w) + c1 * s[7];
  *(float4*)(acc + base) = a0;
  *(float4*)(acc + base + 4) = a1;
  uint4 tw;
  tw.x = pack2(s[0], s[1]); tw.y = pack2(s[2], s[3]);
  tw.z = pack2(s[4], s[5]); tw.w = pack2(s[6], s[7]);
  *(uint4*)(tx1 + base) = tw;
}

__global__ void spmm_first(const int* __restrict__ rowptr, const int2* __restrict__ ecw,
                           const unsigned short* __restrict__ h, unsigned short* __restrict__ tx1,
                           float* __restrict__ acc, const float* __restrict__ cw, int n) {
  int wv = (blockIdx.x * blockDim.x + threadIdx.x) >> 6;
  int lane = threadIdx.x & 63;
  int p = lane & 7, g = lane >> 3;
  int rowA = wv * 2;
  if (rowA >= n) return;
  int rowB = rowA + 1;
  bool hasB = rowB < n;
  float sA[8], sB[8];
  gather_two(rowptr, ecw, h, rowA, hasB ? rowB : rowA, hasB, p, g, sA, sB);
  float c0 = cw[0], c1 = cw[1];
  if (g == 0)
    first_epilogue(h, tx1, acc, c0, c1, (size_t)rowA * NCLS + (p << 3), sA);
  if (g == 1 && hasB)
    first_epilogue(h, tx1, acc, c0, c1, (size_t)rowB * NCLS + (p << 3), sB);
}

__device__ inline void step_epilogue(const unsigned short* __restrict__ prevb,
                                     unsigned short* __restrict__ nextb,
                                     float* __restrict__ acc, float ck, int last,
                                     size_t base, const float s[8]) {
  uint4 pv = *(const uint4*)(prevb + base);
  float t[8];
  t[0] = 2.0f * s[0] - u2f_lo(pv.x); t[1] = 2.0f * s[1] - u2f_hi(pv.x);
  t[2] = 2.0f * s[2] - u2f_lo(pv.y); t[3] = 2.0f * s[3] - u2f_hi(pv.y);
  t[4] = 2.0f * s[4] - u2f_lo(pv.z); t[5] = 2.0f * s[5] - u2f_hi(pv.z);
  t[6] = 2.0f * s[6] - u2f_lo(pv.w); t[7] = 2.0f * s[7] - u2f_hi(pv.w);
  if (!last) {
    uint4 nw;
    nw.x = pack2(t[0], t[1]); nw.y = pack2(t[2], t[3]);
    nw.z = pack2(t[4], t[5]); nw.w = pack2(t[6], t[7]);
    *(uint4*)(nextb + base) = nw;
    float4 a0 = *(const float4*)(acc + base);
    float4 a1 = *(const float4*)(acc + base + 4);
    a0.x = fmaf(ck, t[0], a0.x); a0.y = fmaf(ck, t[1], a0.y);
    a0.z = fmaf(ck, t[2], a0.z); a0.w = fmaf(ck, t[3], a0.w);
    a1.x = fmaf(ck, t[4], a1.x); a1.y = fmaf(ck, t[5], a1.y);
    a1.z = fmaf(ck, t[6], a1.z); a1.w = fmaf(ck, t[7], a1.w);
    *(float4*)(acc + base) = a0;
    *(float4*)(acc + base + 4) = a1;
  } else {
    float4 a0 = *(const float4*)(acc + base);
    float4 a1 = *(const float4*)(acc + base + 4);
    float v[8];
    v[0] = fmaf(ck, t[0], a0.x); v[1] = fmaf(ck, t[1], a0.y);
    v[2] = fmaf(ck, t[2], a0.z); v[3] = fmaf(ck, t[3], a0.w);
    v[4] = fmaf(ck, t[4], a1.x); v[5] = fmaf(ck, t[5], a1.y);
    v[6] = fmaf(ck, t[6], a1.z); v[7] = fmaf(ck, t[7], a1.w);
    float m = v[0];
#pragma unroll
    for (int i = 1; i < 8; ++i) m = fmaxf(m, v[i]);
    m = fmaxf(m, __shfl_xor(m, 1, 64));
    m = fmaxf(m, __shfl_xor(m, 2, 64));
    m = fmaxf(m, __shfl_xor(m, 4, 64));
    float ss = 0.0f;
#pragma unroll
    for (int i = 0; i < 8; ++i) ss += expf(v[i] - m);
    ss += __shfl_xor(ss, 1, 64);
    ss += __shfl_xor(ss, 2, 64);
    ss += __shfl_xor(ss, 4, 64);
    float lg = m + logf(ss);
    float4 o0, o1;
    o0.x = v[0] - lg; o0.y = v[1] - lg; o0.z = v[2] - lg; o0.w = v[3] - lg;
    o1.x = v[4] - lg; o1.y = v[5] - lg; o1.z = v[6] - lg; o1.w = v[7] - lg;
    *(float4*)(acc + base) = o0;
    *(float4*)(acc + base + 4) = o1;
  }
}

__global__ void spmm_step(const int* __restrict__ rowptr, const int2* __restrict__ ecw,
                          const unsigned short* __restrict__ curb,
                          const unsigned short* __restrict__ prevb,
                          unsigned short* __restrict__ nextb, float* __restrict__ acc,
                          const float* __restrict__ cw, int k, int last, int n) {
  int wv = (blockIdx.x * blockDim.x + threadIdx.x) >> 6;
  int lane = threadIdx.x & 63;
  int p = lane & 7, g = lane >> 3;
  int rowA = wv * 2;
  if (rowA >= n) return;
  int rowB = rowA + 1;
  bool hasB = rowB < n;
  float sA[8], sB[8];
  gather_two(rowptr, ecw, curb, rowA, hasB ? rowB : rowA, hasB, p, g, sA, sB);
  float ck = cw[k];
  if (g == 0)
    step_epilogue(prevb, nextb, acc, ck, last, (size_t)rowA * NCLS + (p << 3), sA);
  if (g == 1 && hasB)
    step_epilogue(prevb, nextb, acc, ck, last, (size_t)rowB * NCLS + (p << 3), sB);
}

// ------------------------- launch -------------------------
extern "C" void kernel_launch(void* const* d_in, const int* in_sizes, int n_in,
                              void* d_out, int out_size, void* d_ws, size_t ws_size,
                              hipStream_t stream) {
  const float* x  = (const float*)d_in[0];
  const int*   ei = (const int*)d_in[1];
  const float* W1 = (const float*)d_in[2];
  const float* W2 = (const float*)d_in[3];
  const float* cw = (const float*)d_in[4];
  float* out = (float*)d_out;

  const int n = in_sizes[0] / NFEAT;     // 100000
  const int E = in_sizes[1] / 2;         // 1600000

  size_t off = 0;
  auto alloc = [&](size_t bytes) { size_t o = off; off += (bytes + 255) & ~(size_t)255; return o; };
  char* w = (char*)d_ws;
  size_t o_cnt   = alloc((size_t)n * 4);
  size_t o_self  = alloc((size_t)n * 4);
  size_t o_cur   = alloc((size_t)n * 4);
  size_t o_dinv  = alloc((size_t)n * 4);      // memset region: o_cnt .. o_dinv
  size_t o_rp    = alloc((size_t)(n + 1) * 4);
  size_t o_bs    = alloc(4096 * 4);
  size_t o_w1f   = alloc((size_t)KPAD * NHID * 2);
  size_t o_w2f   = alloc((size_t)NHID * NCLS * 2);
  size_t o_ecw   = alloc((size_t)E * 8);
  size_t o_bufH  = alloc((size_t)n * NCLS * 2);
  size_t o_bufA  = alloc((size_t)n * NCLS * 2);
  size_t o_bufB  = alloc((size_t)n * NCLS * 2);

  int*   cnt    = (int*)(w + o_cnt);
  int*   selfc  = (int*)(w + o_self);
  int*   curi   = (int*)(w + o_cur);
  float* dinv   = (float*)(w + o_dinv);
  int*   rowptr = (int*)(w + o_rp);
  int*   bsums  = (int*)(w + o_bs);
  unsigned short* W1F = (unsigned short*)(w + o_w1f);
  unsigned short* W2F = (unsigned short*)(w + o_w2f);
  int2*  ecw    = (int2*)(w + o_ecw);
  unsigned short* bufH = (unsigned short*)(w + o_bufH);
  unsigned short* bufA = (unsigned short*)(w + o_bufA);
  unsigned short* bufB = (unsigned short*)(w + o_bufB);

  hipMemsetAsync(w + o_cnt, 0, o_dinv - o_cnt, stream);

  const int nb = (n + 255) / 256;

  conv_w1f<<<(KPAD * NHID + 255) / 256, 256, 0, stream>>>(W1, W1F);
  conv_w2f<<<(NHID * NCLS + 255) / 256, 256, 0, stream>>>(W2, W2F);

  edge_count<<<1024, 256, 0, stream>>>(ei, E, cnt, selfc);
  make_dinv<<<nb, 256, 0, stream>>>(cnt, selfc, dinv, n);
  scan_block<<<nb, 256, 0, stream>>>(cnt, rowptr, bsums, n);
  scan_sums<<<1, 1, 0, stream>>>(bsums, nb, rowptr);
  scan_add<<<nb, 256, 0, stream>>>(rowptr, bsums, n);
  scatter_edges<<<1024, 256, 0, stream>>>(ei, E, dinv, rowptr, curi, ecw);

  mlp_mfma<<<(n + 63) / 64, 256, 0, stream>>>(x, W1F, W2F, bufH, n);

  // 2 rows per wave, 4 waves per block
  const int waves = (n + 1) / 2;
  const int spmm_blocks = (waves + 3) / 4;
  spmm_first<<<spmm_blocks, 256, 0, stream>>>(rowptr, ecw, bufH, bufA, out, cw, n);

  unsigned short* P = bufH;
  unsigned short* C = bufA;
  unsigned short* N = bufB;
  for (int k = 2; k <= KPOLY; ++k) {
    spmm_step<<<spmm_blocks, 256, 0, stream>>>(rowptr, ecw, C, P, N, out, cw, k,
                                               (k == KPOLY) ? 1 : 0, n);
    unsigned short* t = P; P = C; C = N; N = t;
  }
}

// Round 15
// 723.122 us; speedup vs baseline: 2.3495x; 1.0065x over previous
//
#include <hip/hip_runtime.h>
#include <hip/hip_bf16.h>
#include <math.h>

#define NFEAT 500
#define KPAD  512
#define NHID  256
#define NCLS  64
#define KPOLY 10

typedef __attribute__((ext_vector_type(8))) short short8;
typedef __attribute__((ext_vector_type(4))) float f32x4;

__device__ inline unsigned short bf16_rn(float v) {
  unsigned u = __float_as_uint(v);
  return (unsigned short)((u + 0x7FFFu + ((u >> 16) & 1u)) >> 16);
}
__device__ inline float u2f_lo(unsigned u) { return __uint_as_float(u << 16); }
__device__ inline float u2f_hi(unsigned u) { return __uint_as_float(u & 0xFFFF0000u); }
__device__ inline unsigned pack2(float a, float b) {
  return (unsigned)bf16_rn(a) | ((unsigned)bf16_rn(b) << 16);
}

// ---------- weight pre-conversion into MFMA fragment layout (bf16 single) ----------
__global__ void conv_w1f(const float* __restrict__ W1, unsigned short* __restrict__ Fh) {
  int i = blockIdx.x * 256 + threadIdx.x;
  if (i >= KPAD * NHID) return;
  int kg = i >> 11, c = (i >> 3) & 255, kin = i & 7;
  int k = kg * 8 + kin;
  float v = (k < NFEAT) ? W1[c * NFEAT + k] : 0.0f;
  Fh[i] = bf16_rn(v);
}
__global__ void conv_w2f(const float* __restrict__ W2, unsigned short* __restrict__ F) {
  int i = blockIdx.x * 256 + threadIdx.x;
  if (i >= NHID * NCLS) return;
  int kg = i >> 9, c = (i >> 3) & 63, kin = i & 7;
  int k = kg * 8 + kin;
  F[i] = bf16_rn(W2[c * NHID + k]);
}

// ------------------------- CSR build -------------------------
__global__ void edge_count(const int* __restrict__ ei, int E,
                           int* __restrict__ cnt, int* __restrict__ selfc) {
  int stride = gridDim.x * blockDim.x;
  for (int e = blockIdx.x * blockDim.x + threadIdx.x; e < E; e += stride) {
    int r = ei[e], c = ei[E + e];
    atomicAdd(&cnt[r], 1);
    if (r == c) atomicAdd(&selfc[r], 1);
  }
}

__global__ void make_dinv(const int* __restrict__ cnt, const int* __restrict__ selfc,
                          float* __restrict__ dinv, int n) {
  int i = blockIdx.x * blockDim.x + threadIdx.x;
  if (i < n) {
    int d = cnt[i] - selfc[i];
    dinv[i] = (d > 0) ? rsqrtf((float)d) : 0.0f;
  }
}

__global__ void scan_block(const int* __restrict__ cnt, int* __restrict__ rowptr,
                           int* __restrict__ bsums, int n) {
  __shared__ int s[256];
  int i = blockIdx.x * 256 + threadIdx.x;
  int v = (i < n) ? cnt[i] : 0;
  s[threadIdx.x] = v;
  __syncthreads();
  for (int off = 1; off < 256; off <<= 1) {
    int t = (threadIdx.x >= (unsigned)off) ? s[threadIdx.x - off] : 0;
    __syncthreads();
    s[threadIdx.x] += t;
    __syncthreads();
  }
  if (i < n) rowptr[i + 1] = s[threadIdx.x];
  if (threadIdx.x == 255) bsums[blockIdx.x] = s[255];
}

__global__ void scan_sums(int* __restrict__ bsums, int nb, int* __restrict__ rowptr) {
  if (threadIdx.x == 0 && blockIdx.x == 0) {
    int run = 0;
    for (int b = 0; b < nb; ++b) { int t = bsums[b]; bsums[b] = run; run += t; }
    rowptr[0] = 0;
  }
}

__global__ void scan_add(int* __restrict__ rowptr, const int* __restrict__ bsums, int n) {
  int i = blockIdx.x * 256 + threadIdx.x;
  if (i < n) rowptr[i + 1] += bsums[i >> 8];
}

__global__ void scatter_edges(const int* __restrict__ ei, int E,
                              const float* __restrict__ dinv,
                              const int* __restrict__ rowptr, int* __restrict__ cur,
                              int2* __restrict__ ecw) {
  int stride = gridDim.x * blockDim.x;
  for (int e = blockIdx.x * blockDim.x + threadIdx.x; e < E; e += stride) {
    int r = ei[e], c = ei[E + e];
    int pos = rowptr[r] + atomicAdd(&cur[r], 1);
    float wt = (r != c) ? (-dinv[r] * dinv[c]) : 0.0f;
    ecw[pos] = make_int2(c, __float_as_int(wt));
  }
}

// ------------------------- fused MLP via MFMA (all-bf16, non-persistent) ------------------
__global__ __launch_bounds__(256, 5) void mlp_mfma(
    const float* __restrict__ x, const unsigned short* __restrict__ W1F,
    const unsigned short* __restrict__ W2F, unsigned short* __restrict__ hout, int n)
{
  __shared__ union {
    struct { unsigned short A[2][4][64][8]; } g1;   // 8 KB (double-buffered A tile)
    struct { unsigned short A2[32][64][8]; } g2;    // 32 KB (relu(h) frags)
  } u;

  const int tid = threadIdx.x;
  const int w = tid >> 6;
  const int l = tid & 63;
  const int l15 = l & 15, l4 = l >> 4;
  const int row0 = blockIdx.x * 64;
  const f32x4 zf = {0.0f, 0.0f, 0.0f, 0.0f};

  f32x4 acc[4][4];
#pragma unroll
  for (int i = 0; i < 4; ++i)
#pragma unroll
    for (int j = 0; j < 4; ++j) acc[i][j] = zf;

  // prologue: stage tile 0 into buffer 0
#pragma unroll
  for (int s = 0; s < 2; ++s) {
    int f = tid + s * 256;
    int r = f >> 3, slot = f & 7;
    int gr = row0 + r, gk = slot * 4;
    float4 v = make_float4(0.f, 0.f, 0.f, 0.f);
    if (gr < n && gk + 3 < NFEAT)
      v = *(const float4*)&x[(size_t)gr * NFEAT + gk];
    int kg = slot >> 1, kin0 = (slot & 1) * 4;
    *(uint2*)&u.g1.A[0][kg][r][kin0] = make_uint2(pack2(v.x, v.y), pack2(v.z, v.w));
  }
  __syncthreads();

  for (int t = 0; t < 16; ++t) {
    const int cur = t & 1;
    float4 va[2];
    if (t < 15) {
#pragma unroll
      for (int s = 0; s < 2; ++s) {
        int f = tid + s * 256;
        int r = f >> 3, slot = f & 7;
        int gr = row0 + r, gk = (t + 1) * 32 + slot * 4;
        va[s] = make_float4(0.f, 0.f, 0.f, 0.f);
        if (gr < n && gk + 3 < NFEAT)
          va[s] = *(const float4*)&x[(size_t)gr * NFEAT + gk];
      }
    }
    short8 bH[4];
#pragma unroll
    for (int nf = 0; nf < 4; ++nf) {
      size_t bi = (size_t)t * 8192 + ((size_t)l4 * 256 + w * 64 + nf * 16 + l15) * 8;
      bH[nf] = *(const short8*)(W1F + bi);
    }
#pragma unroll
    for (int mf = 0; mf < 4; ++mf) {
      short8 aH = *(const short8*)&u.g1.A[cur][l4][mf * 16 + l15][0];
#pragma unroll
      for (int nf = 0; nf < 4; ++nf)
        acc[mf][nf] = __builtin_amdgcn_mfma_f32_16x16x32_bf16(aH, bH[nf], acc[mf][nf], 0, 0, 0);
    }
    if (t < 15) {
#pragma unroll
      for (int s = 0; s < 2; ++s) {
        int f = tid + s * 256;
        int r = f >> 3, slot = f & 7;
        int kg = slot >> 1, kin0 = (slot & 1) * 4;
        *(uint2*)&u.g1.A[cur ^ 1][kg][r][kin0] =
            make_uint2(pack2(va[s].x, va[s].y), pack2(va[s].z, va[s].w));
      }
    }
    __syncthreads();
  }

  // ---- exchange relu(h) as bf16 A2 frags ----
#pragma unroll
  for (int mf = 0; mf < 4; ++mf)
#pragma unroll
    for (int nf = 0; nf < 4; ++nf) {
      int col = w * 64 + nf * 16 + l15;
      int kg = col >> 3, kin = col & 7;
#pragma unroll
      for (int j = 0; j < 4; ++j) {
        float vv = fmaxf(acc[mf][nf][j], 0.0f);
        u.g2.A2[kg][mf * 16 + l4 * 4 + j][kin] = bf16_rn(vv);
      }
    }
  __syncthreads();

  // ---- GEMM2 ----
  f32x4 acc2[4];
#pragma unroll
  for (int i = 0; i < 4; ++i) acc2[i] = zf;
#pragma unroll
  for (int ks = 0; ks < 8; ++ks) {
    short8 a2 = *(const short8*)&u.g2.A2[ks * 4 + l4][w * 16 + l15][0];
#pragma unroll
    for (int nf2 = 0; nf2 < 4; ++nf2) {
      size_t bi = ((size_t)(ks * 4 + l4) * 64 + nf2 * 16 + l15) * 8;
      short8 b2 = *(const short8*)(W2F + bi);
      acc2[nf2] = __builtin_amdgcn_mfma_f32_16x16x32_bf16(a2, b2, acc2[nf2], 0, 0, 0);
    }
  }
#pragma unroll
  for (int nf2 = 0; nf2 < 4; ++nf2)
#pragma unroll
    for (int j = 0; j < 4; ++j) {
      int r = row0 + w * 16 + l4 * 4 + j;
      if (r < n) hout[(size_t)r * NCLS + nf2 * 16 + l15] = bf16_rn(acc2[nf2][j]);
    }
}

// ---------------- SpMM: 2 rows per wave, 8 lanes/edge; deferred comb ----------------
__device__ inline void acc8(float s[8], float w, uint4 h) {
  s[0] = fmaf(w, u2f_lo(h.x), s[0]); s[1] = fmaf(w, u2f_hi(h.x), s[1]);
  s[2] = fmaf(w, u2f_lo(h.y), s[2]); s[3] = fmaf(w, u2f_hi(h.y), s[3]);
  s[4] = fmaf(w, u2f_lo(h.z), s[4]); s[5] = fmaf(w, u2f_hi(h.z), s[5]);
  s[6] = fmaf(w, u2f_lo(h.w), s[6]); s[7] = fmaf(w, u2f_hi(h.w), s[7]);
}

__device__ inline void gather_two(const int* __restrict__ rowptr,
                                  const int2* __restrict__ ecw,
                                  const unsigned short* __restrict__ src,
                                  int rowA, int rowB, bool hasB, int p, int g,
                                  float sA[8], float sB[8]) {
#pragma unroll
  for (int i = 0; i < 8; ++i) { sA[i] = 0.0f; sB[i] = 0.0f; }
  int e0a = rowptr[rowA], e1a = rowptr[rowA + 1];
  int e0b = 0, e1b = 0;
  if (hasB) { e0b = rowptr[rowB]; e1b = rowptr[rowB + 1]; }
  int ita = (e1a - e0a + 15) >> 4;
  int itb = (e1b - e0b + 15) >> 4;
  int itm = (ita > itb) ? ita : itb;
  const unsigned short* bp = src + (p << 3);
  for (int it = 0; it < itm; ++it) {
    int ba = e0a + it * 16, bb = e0b + it * 16;
    int eeA0 = ba + g,     eeA1 = ba + 8 + g;
    int eeB0 = bb + g,     eeB1 = bb + 8 + g;
    int iA0 = max(min(eeA0, e1a - 1), 0);
    int iA1 = max(min(eeA1, e1a - 1), 0);
    int iB0 = max(min(eeB0, e1b - 1), 0);
    int iB1 = max(min(eeB1, e1b - 1), 0);
    int2 tA0 = ecw[iA0];
    int2 tA1 = ecw[iA1];
    int2 tB0 = ecw[iB0];
    int2 tB1 = ecw[iB1];
    uint4 hA0 = *(const uint4*)(bp + (((size_t)tA0.x) << 6));
    uint4 hA1 = *(const uint4*)(bp + (((size_t)tA1.x) << 6));
    uint4 hB0 = *(const uint4*)(bp + (((size_t)tB0.x) << 6));
    uint4 hB1 = *(const uint4*)(bp + (((size_t)tB1.x) << 6));
    float wA0 = (eeA0 < e1a) ? __int_as_float(tA0.y) : 0.0f;
    float wA1 = (eeA1 < e1a) ? __int_as_float(tA1.y) : 0.0f;
    float wB0 = (eeB0 < e1b) ? __int_as_float(tB0.y) : 0.0f;
    float wB1 = (eeB1 < e1b) ? __int_as_float(tB1.y) : 0.0f;
    acc8(sA, wA0, hA0);
    acc8(sA, wA1, hA1);
    acc8(sB, wB0, hB0);
    acc8(sB, wB1, hB1);
  }
#pragma unroll
  for (int i = 0; i < 8; ++i) {
    sA[i] += __shfl_xor(sA[i], 8, 64);
    sA[i] += __shfl_xor(sA[i], 16, 64);
    sA[i] += __shfl_xor(sA[i], 32, 64);
    sB[i] += __shfl_xor(sB[i], 8, 64);
    sB[i] += __shfl_xor(sB[i], 16, 64);
    sB[i] += __shfl_xor(sB[i], 32, 64);
  }
}

// pass 1: T1 = L~ T0 (just the gather result)
__global__ void spmm_first(const int* __restrict__ rowptr, const int2* __restrict__ ecw,
                           const unsigned short* __restrict__ t0,
                           unsigned short* __restrict__ t1, int n) {
  int wv = (blockIdx.x * blockDim.x + threadIdx.x) >> 6;
  int lane = threadIdx.x & 63;
  int p = lane & 7, g = lane >> 3;
  int rowA = wv * 2;
  if (rowA >= n) return;
  int rowB = rowA + 1;
  bool hasB = rowB < n;
  float sA[8], sB[8];
  gather_two(rowptr, ecw, t0, rowA, hasB ? rowB : rowA, hasB, p, g, sA, sB);
  if (g == 0) {
    size_t base = (size_t)rowA * NCLS + (p << 3);
    uint4 tw;
    tw.x = pack2(sA[0], sA[1]); tw.y = pack2(sA[2], sA[3]);
    tw.z = pack2(sA[4], sA[5]); tw.w = pack2(sA[6], sA[7]);
    *(uint4*)(t1 + base) = tw;
  }
  if (g == 1 && hasB) {
    size_t base = (size_t)rowB * NCLS + (p << 3);
    uint4 tw;
    tw.x = pack2(sB[0], sB[1]); tw.y = pack2(sB[2], sB[3]);
    tw.z = pack2(sB[4], sB[5]); tw.w = pack2(sB[6], sB[7]);
    *(uint4*)(t1 + base) = tw;
  }
}

__device__ inline void step_write(const unsigned short* __restrict__ prevb,
                                  unsigned short* __restrict__ nextb,
                                  size_t base, const float s[8]) {
  uint4 pv = *(const uint4*)(prevb + base);
  uint4 nw;
  nw.x = pack2(2.0f * s[0] - u2f_lo(pv.x), 2.0f * s[1] - u2f_hi(pv.x));
  nw.y = pack2(2.0f * s[2] - u2f_lo(pv.y), 2.0f * s[3] - u2f_hi(pv.y));
  nw.z = pack2(2.0f * s[4] - u2f_lo(pv.z), 2.0f * s[5] - u2f_hi(pv.z));
  nw.w = pack2(2.0f * s[6] - u2f_lo(pv.w), 2.0f * s[7] - u2f_hi(pv.w));
  *(uint4*)(nextb + base) = nw;
}

__global__ void spmm_step(const int* __restrict__ rowptr, const int2* __restrict__ ecw,
                          const unsigned short* __restrict__ curb,
                          const unsigned short* __restrict__ prevb,
                          unsigned short* __restrict__ nextb, int n) {
  int wv = (blockIdx.x * blockDim.x + threadIdx.x) >> 6;
  int lane = threadIdx.x & 63;
  int p = lane & 7, g = lane >> 3;
  int rowA = wv * 2;
  if (rowA >= n) return;
  int rowB = rowA + 1;
  bool hasB = rowB < n;
  float sA[8], sB[8];
  gather_two(rowptr, ecw, curb, rowA, hasB ? rowB : rowA, hasB, p, g, sA, sB);
  if (g == 0)
    step_write(prevb, nextb, (size_t)rowA * NCLS + (p << 3), sA);
  if (g == 1 && hasB)
    step_write(prevb, nextb, (size_t)rowB * NCLS + (p << 3), sB);
}

// ---- final: v = sum_k cw[k]*T_k, then log-softmax, write fp32 out ----
__global__ void final_comb(const unsigned short* __restrict__ T, size_t tstride,
                           const float* __restrict__ cw, float* __restrict__ out, int n) {
  int wv = (blockIdx.x * blockDim.x + threadIdx.x) >> 6;
  int ch = threadIdx.x & 63;
  if (wv >= n) return;
  size_t idx = (size_t)wv * NCLS + ch;
  float v = 0.0f;
#pragma unroll
  for (int k = 0; k <= KPOLY; ++k) {
    unsigned short tv = T[(size_t)k * tstride + idx];
    v = fmaf(cw[k], __uint_as_float(((unsigned)tv) << 16), v);
  }
  float m = v;
#pragma unroll
  for (int off = 32; off > 0; off >>= 1) m = fmaxf(m, __shfl_xor(m, off, 64));
  float ex = expf(v - m);
  float ss = ex;
#pragma unroll
  for (int off = 32; off > 0; off >>= 1) ss += __shfl_xor(ss, off, 64);
  out[idx] = v - m - logf(ss);
}

// ------------------------- launch -------------------------
extern "C" void kernel_launch(void* const* d_in, const int* in_sizes, int n_in,
                              void* d_out, int out_size, void* d_ws, size_t ws_size,
                              hipStream_t stream) {
  const float* x  = (const float*)d_in[0];
  const int*   ei = (const int*)d_in[1];
  const float* W1 = (const float*)d_in[2];
  const float* W2 = (const float*)d_in[3];
  const float* cw = (const float*)d_in[4];
  float* out = (float*)d_out;

  const int n = in_sizes[0] / NFEAT;     // 100000
  const int E = in_sizes[1] / 2;         // 1600000

  size_t off = 0;
  auto alloc = [&](size_t bytes) { size_t o = off; off += (bytes + 255) & ~(size_t)255; return o; };
  char* w = (char*)d_ws;
  size_t o_cnt   = alloc((size_t)n * 4);
  size_t o_self  = alloc((size_t)n * 4);
  size_t o_cur   = alloc((size_t)n * 4);
  size_t o_dinv  = alloc((size_t)n * 4);      // memset region: o_cnt .. o_dinv
  size_t o_rp    = alloc((size_t)(n + 1) * 4);
  size_t o_bs    = alloc(4096 * 4);
  size_t o_w1f   = alloc((size_t)KPAD * NHID * 2);
  size_t o_w2f   = alloc((size_t)NHID * NCLS * 2);
  size_t o_ecw   = alloc((size_t)E * 8);
  // 11 T-term buffers, equal stride (elements)
  const size_t tsz_b = (((size_t)n * NCLS * 2) + 255) & ~(size_t)255;
  size_t o_T     = alloc(tsz_b * (KPOLY + 1));
  const size_t tstride = tsz_b / 2;   // elements per buffer

  int*   cnt    = (int*)(w + o_cnt);
  int*   selfc  = (int*)(w + o_self);
  int*   curi   = (int*)(w + o_cur);
  float* dinv   = (float*)(w + o_dinv);
  int*   rowptr = (int*)(w + o_rp);
  int*   bsums  = (int*)(w + o_bs);
  unsigned short* W1F = (unsigned short*)(w + o_w1f);
  unsigned short* W2F = (unsigned short*)(w + o_w2f);
  int2*  ecw    = (int2*)(w + o_ecw);
  unsigned short* T = (unsigned short*)(w + o_T);
  auto Tk = [&](int k) { return T + (size_t)k * tstride; };

  hipMemsetAsync(w + o_cnt, 0, o_dinv - o_cnt, stream);

  const int nb = (n + 255) / 256;

  conv_w1f<<<(KPAD * NHID + 255) / 256, 256, 0, stream>>>(W1, W1F);
  conv_w2f<<<(NHID * NCLS + 255) / 256, 256, 0, stream>>>(W2, W2F);

  edge_count<<<1024, 256, 0, stream>>>(ei, E, cnt, selfc);
  make_dinv<<<nb, 256, 0, stream>>>(cnt, selfc, dinv, n);
  scan_block<<<nb, 256, 0, stream>>>(cnt, rowptr, bsums, n);
  scan_sums<<<1, 1, 0, stream>>>(bsums, nb, rowptr);
  scan_add<<<nb, 256, 0, stream>>>(rowptr, bsums, n);
  scatter_edges<<<1024, 256, 0, stream>>>(ei, E, dinv, rowptr, curi, ecw);

  mlp_mfma<<<(n + 63) / 64, 256, 0, stream>>>(x, W1F, W2F, Tk(0), n);

  // 2 rows per wave, 4 waves per block
  const int waves = (n + 1) / 2;
  const int spmm_blocks = (waves + 3) / 4;
  spmm_first<<<spmm_blocks, 256, 0, stream>>>(rowptr, ecw, Tk(0), Tk(1), n);
  for (int k = 2; k <= KPOLY; ++k) {
    spmm_step<<<spmm_blocks, 256, 0, stream>>>(rowptr, ecw, Tk(k - 1), Tk(k - 2), Tk(k), n);
  }

  final_comb<<<(n + 3) / 4, 256, 0, stream>>>(T, tstride, cw, out, n);
}

// Round 16
// 674.466 us; speedup vs baseline: 2.5190x; 1.0721x over previous
//
#include <hip/hip_runtime.h>
#include <hip/hip_bf16.h>
#include <math.h>

#define NFEAT 500
#define KPAD  512
#define NHID  256
#define NCLS  64
#define KPOLY 10

typedef __attribute__((ext_vector_type(8))) short short8;
typedef __attribute__((ext_vector_type(4))) float f32x4;

__device__ inline unsigned short bf16_rn(float v) {
  unsigned u = __float_as_uint(v);
  return (unsigned short)((u + 0x7FFFu + ((u >> 16) & 1u)) >> 16);
}
__device__ inline float u2f_lo(unsigned u) { return __uint_as_float(u << 16); }
__device__ inline float u2f_hi(unsigned u) { return __uint_as_float(u & 0xFFFF0000u); }
__device__ inline unsigned pack2(float a, float b) {
  return (unsigned)bf16_rn(a) | ((unsigned)bf16_rn(b) << 16);
}

// ---------- weight pre-conversion into MFMA fragment layout (bf16 single) ----------
__global__ void conv_w1f(const float* __restrict__ W1, unsigned short* __restrict__ Fh) {
  int i = blockIdx.x * 256 + threadIdx.x;
  if (i >= KPAD * NHID) return;
  int kg = i >> 11, c = (i >> 3) & 255, kin = i & 7;
  int k = kg * 8 + kin;
  float v = (k < NFEAT) ? W1[c * NFEAT + k] : 0.0f;
  Fh[i] = bf16_rn(v);
}
__global__ void conv_w2f(const float* __restrict__ W2, unsigned short* __restrict__ F) {
  int i = blockIdx.x * 256 + threadIdx.x;
  if (i >= NHID * NCLS) return;
  int kg = i >> 9, c = (i >> 3) & 63, kin = i & 7;
  int k = kg * 8 + kin;
  F[i] = bf16_rn(W2[c * NHID + k]);
}

// ------------------------- CSR build -------------------------
__global__ void edge_count(const int* __restrict__ ei, int E,
                           int* __restrict__ cnt, int* __restrict__ selfc) {
  int stride = gridDim.x * blockDim.x;
  for (int e = blockIdx.x * blockDim.x + threadIdx.x; e < E; e += stride) {
    int r = ei[e], c = ei[E + e];
    atomicAdd(&cnt[r], 1);
    if (r == c) atomicAdd(&selfc[r], 1);
  }
}

__global__ void make_dinv(const int* __restrict__ cnt, const int* __restrict__ selfc,
                          float* __restrict__ dinv, int n) {
  int i = blockIdx.x * blockDim.x + threadIdx.x;
  if (i < n) {
    int d = cnt[i] - selfc[i];
    dinv[i] = (d > 0) ? rsqrtf((float)d) : 0.0f;
  }
}

__global__ void scan_block(const int* __restrict__ cnt, int* __restrict__ rowptr,
                           int* __restrict__ bsums, int n) {
  __shared__ int s[256];
  int i = blockIdx.x * 256 + threadIdx.x;
  int v = (i < n) ? cnt[i] : 0;
  s[threadIdx.x] = v;
  __syncthreads();
  for (int off = 1; off < 256; off <<= 1) {
    int t = (threadIdx.x >= (unsigned)off) ? s[threadIdx.x - off] : 0;
    __syncthreads();
    s[threadIdx.x] += t;
    __syncthreads();
  }
  if (i < n) rowptr[i + 1] = s[threadIdx.x];
  if (threadIdx.x == 255) bsums[blockIdx.x] = s[255];
}

__global__ void scan_sums(int* __restrict__ bsums, int nb, int* __restrict__ rowptr) {
  if (threadIdx.x == 0 && blockIdx.x == 0) {
    int run = 0;
    for (int b = 0; b < nb; ++b) { int t = bsums[b]; bsums[b] = run; run += t; }
    rowptr[0] = 0;
  }
}

__global__ void scan_add(int* __restrict__ rowptr, const int* __restrict__ bsums, int n) {
  int i = blockIdx.x * 256 + threadIdx.x;
  if (i < n) rowptr[i + 1] += bsums[i >> 8];
}

__global__ void scatter_edges(const int* __restrict__ ei, int E,
                              const float* __restrict__ dinv,
                              const int* __restrict__ rowptr, int* __restrict__ cur,
                              int2* __restrict__ ecw) {
  int stride = gridDim.x * blockDim.x;
  for (int e = blockIdx.x * blockDim.x + threadIdx.x; e < E; e += stride) {
    int r = ei[e], c = ei[E + e];
    int pos = rowptr[r] + atomicAdd(&cur[r], 1);
    float wt = (r != c) ? (-dinv[r] * dinv[c]) : 0.0f;
    ecw[pos] = make_int2(c, __float_as_int(wt));
  }
}

// ------------------------- fused MLP via MFMA (all-bf16, non-persistent) ------------------
// One 64-row tile per block; double-buffered A staging, 1 barrier/K-step; B from global.
// launch_bounds(256,4): VGPR cap 128 -- 64-reg accumulator must NOT spill (r13/r15 lesson).
__global__ __launch_bounds__(256, 4) void mlp_mfma(
    const float* __restrict__ x, const unsigned short* __restrict__ W1F,
    const unsigned short* __restrict__ W2F, unsigned short* __restrict__ hout, int n)
{
  __shared__ union {
    struct { unsigned short A[2][4][64][8]; } g1;   // 8 KB (double-buffered A tile)
    struct { unsigned short A2[32][64][8]; } g2;    // 32 KB (relu(h) frags)
  } u;

  const int tid = threadIdx.x;
  const int w = tid >> 6;
  const int l = tid & 63;
  const int l15 = l & 15, l4 = l >> 4;
  const int row0 = blockIdx.x * 64;
  const f32x4 zf = {0.0f, 0.0f, 0.0f, 0.0f};

  f32x4 acc[4][4];
#pragma unroll
  for (int i = 0; i < 4; ++i)
#pragma unroll
    for (int j = 0; j < 4; ++j) acc[i][j] = zf;

  // prologue: stage tile 0 into buffer 0
#pragma unroll
  for (int s = 0; s < 2; ++s) {
    int f = tid + s * 256;
    int r = f >> 3, slot = f & 7;
    int gr = row0 + r, gk = slot * 4;
    float4 v = make_float4(0.f, 0.f, 0.f, 0.f);
    if (gr < n && gk + 3 < NFEAT)
      v = *(const float4*)&x[(size_t)gr * NFEAT + gk];
    int kg = slot >> 1, kin0 = (slot & 1) * 4;
    *(uint2*)&u.g1.A[0][kg][r][kin0] = make_uint2(pack2(v.x, v.y), pack2(v.z, v.w));
  }
  __syncthreads();

  for (int t = 0; t < 16; ++t) {
    const int cur = t & 1;
    float4 va[2];
    if (t < 15) {
#pragma unroll
      for (int s = 0; s < 2; ++s) {
        int f = tid + s * 256;
        int r = f >> 3, slot = f & 7;
        int gr = row0 + r, gk = (t + 1) * 32 + slot * 4;
        va[s] = make_float4(0.f, 0.f, 0.f, 0.f);
        if (gr < n && gk + 3 < NFEAT)
          va[s] = *(const float4*)&x[(size_t)gr * NFEAT + gk];
      }
    }
    short8 bH[4];
#pragma unroll
    for (int nf = 0; nf < 4; ++nf) {
      size_t bi = (size_t)t * 8192 + ((size_t)l4 * 256 + w * 64 + nf * 16 + l15) * 8;
      bH[nf] = *(const short8*)(W1F + bi);
    }
#pragma unroll
    for (int mf = 0; mf < 4; ++mf) {
      short8 aH = *(const short8*)&u.g1.A[cur][l4][mf * 16 + l15][0];
#pragma unroll
      for (int nf = 0; nf < 4; ++nf)
        acc[mf][nf] = __builtin_amdgcn_mfma_f32_16x16x32_bf16(aH, bH[nf], acc[mf][nf], 0, 0, 0);
    }
    if (t < 15) {
#pragma unroll
      for (int s = 0; s < 2; ++s) {
        int f = tid + s * 256;
        int r = f >> 3, slot = f & 7;
        int kg = slot >> 1, kin0 = (slot & 1) * 4;
        *(uint2*)&u.g1.A[cur ^ 1][kg][r][kin0] =
            make_uint2(pack2(va[s].x, va[s].y), pack2(va[s].z, va[s].w));
      }
    }
    __syncthreads();
  }

  // ---- exchange relu(h) as bf16 A2 frags ----
#pragma unroll
  for (int mf = 0; mf < 4; ++mf)
#pragma unroll
    for (int nf = 0; nf < 4; ++nf) {
      int col = w * 64 + nf * 16 + l15;
      int kg = col >> 3, kin = col & 7;
#pragma unroll
      for (int j = 0; j < 4; ++j) {
        float vv = fmaxf(acc[mf][nf][j], 0.0f);
        u.g2.A2[kg][mf * 16 + l4 * 4 + j][kin] = bf16_rn(vv);
      }
    }
  __syncthreads();

  // ---- GEMM2 ----
  f32x4 acc2[4];
#pragma unroll
  for (int i = 0; i < 4; ++i) acc2[i] = zf;
#pragma unroll
  for (int ks = 0; ks < 8; ++ks) {
    short8 a2 = *(const short8*)&u.g2.A2[ks * 4 + l4][w * 16 + l15][0];
#pragma unroll
    for (int nf2 = 0; nf2 < 4; ++nf2) {
      size_t bi = ((size_t)(ks * 4 + l4) * 64 + nf2 * 16 + l15) * 8;
      short8 b2 = *(const short8*)(W2F + bi);
      acc2[nf2] = __builtin_amdgcn_mfma_f32_16x16x32_bf16(a2, b2, acc2[nf2], 0, 0, 0);
    }
  }
#pragma unroll
  for (int nf2 = 0; nf2 < 4; ++nf2)
#pragma unroll
    for (int j = 0; j < 4; ++j) {
      int r = row0 + w * 16 + l4 * 4 + j;
      if (r < n) hout[(size_t)r * NCLS + nf2 * 16 + l15] = bf16_rn(acc2[nf2][j]);
    }
}

// ---------------- SpMM: 2 rows per wave, 8 lanes/edge; deferred comb ----------------
__device__ inline void acc8(float s[8], float w, uint4 h) {
  s[0] = fmaf(w, u2f_lo(h.x), s[0]); s[1] = fmaf(w, u2f_hi(h.x), s[1]);
  s[2] = fmaf(w, u2f_lo(h.y), s[2]); s[3] = fmaf(w, u2f_hi(h.y), s[3]);
  s[4] = fmaf(w, u2f_lo(h.z), s[4]); s[5] = fmaf(w, u2f_hi(h.z), s[5]);
  s[6] = fmaf(w, u2f_lo(h.w), s[6]); s[7] = fmaf(w, u2f_hi(h.w), s[7]);
}

__device__ inline void gather_two(const int* __restrict__ rowptr,
                                  const int2* __restrict__ ecw,
                                  const unsigned short* __restrict__ src,
                                  int rowA, int rowB, bool hasB, int p, int g,
                                  float sA[8], float sB[8]) {
#pragma unroll
  for (int i = 0; i < 8; ++i) { sA[i] = 0.0f; sB[i] = 0.0f; }
  int e0a = rowptr[rowA], e1a = rowptr[rowA + 1];
  int e0b = 0, e1b = 0;
  if (hasB) { e0b = rowptr[rowB]; e1b = rowptr[rowB + 1]; }
  int ita = (e1a - e0a + 15) >> 4;
  int itb = (e1b - e0b + 15) >> 4;
  int itm = (ita > itb) ? ita : itb;
  const unsigned short* bp = src + (p << 3);
  for (int it = 0; it < itm; ++it) {
    int ba = e0a + it * 16, bb = e0b + it * 16;
    int eeA0 = ba + g,     eeA1 = ba + 8 + g;
    int eeB0 = bb + g,     eeB1 = bb + 8 + g;
    int iA0 = max(min(eeA0, e1a - 1), 0);
    int iA1 = max(min(eeA1, e1a - 1), 0);
    int iB0 = max(min(eeB0, e1b - 1), 0);
    int iB1 = max(min(eeB1, e1b - 1), 0);
    int2 tA0 = ecw[iA0];
    int2 tA1 = ecw[iA1];
    int2 tB0 = ecw[iB0];
    int2 tB1 = ecw[iB1];
    uint4 hA0 = *(const uint4*)(bp + (((size_t)tA0.x) << 6));
    uint4 hA1 = *(const uint4*)(bp + (((size_t)tA1.x) << 6));
    uint4 hB0 = *(const uint4*)(bp + (((size_t)tB0.x) << 6));
    uint4 hB1 = *(const uint4*)(bp + (((size_t)tB1.x) << 6));
    float wA0 = (eeA0 < e1a) ? __int_as_float(tA0.y) : 0.0f;
    float wA1 = (eeA1 < e1a) ? __int_as_float(tA1.y) : 0.0f;
    float wB0 = (eeB0 < e1b) ? __int_as_float(tB0.y) : 0.0f;
    float wB1 = (eeB1 < e1b) ? __int_as_float(tB1.y) : 0.0f;
    acc8(sA, wA0, hA0);
    acc8(sA, wA1, hA1);
    acc8(sB, wB0, hB0);
    acc8(sB, wB1, hB1);
  }
#pragma unroll
  for (int i = 0; i < 8; ++i) {
    sA[i] += __shfl_xor(sA[i], 8, 64);
    sA[i] += __shfl_xor(sA[i], 16, 64);
    sA[i] += __shfl_xor(sA[i], 32, 64);
    sB[i] += __shfl_xor(sB[i], 8, 64);
    sB[i] += __shfl_xor(sB[i], 16, 64);
    sB[i] += __shfl_xor(sB[i], 32, 64);
  }
}

// pass 1: T1 = L~ T0
__global__ void spmm_first(const int* __restrict__ rowptr, const int2* __restrict__ ecw,
                           const unsigned short* __restrict__ t0,
                           unsigned short* __restrict__ t1, int n) {
  int wv = (blockIdx.x * blockDim.x + threadIdx.x) >> 6;
  int lane = threadIdx.x & 63;
  int p = lane & 7, g = lane >> 3;
  int rowA = wv * 2;
  if (rowA >= n) return;
  int rowB = rowA + 1;
  bool hasB = rowB < n;
  float sA[8], sB[8];
  gather_two(rowptr, ecw, t0, rowA, hasB ? rowB : rowA, hasB, p, g, sA, sB);
  if (g == 0) {
    size_t base = (size_t)rowA * NCLS + (p << 3);
    uint4 tw;
    tw.x = pack2(sA[0], sA[1]); tw.y = pack2(sA[2], sA[3]);
    tw.z = pack2(sA[4], sA[5]); tw.w = pack2(sA[6], sA[7]);
    *(uint4*)(t1 + base) = tw;
  }
  if (g == 1 && hasB) {
    size_t base = (size_t)rowB * NCLS + (p << 3);
    uint4 tw;
    tw.x = pack2(sB[0], sB[1]); tw.y = pack2(sB[2], sB[3]);
    tw.z = pack2(sB[4], sB[5]); tw.w = pack2(sB[6], sB[7]);
    *(uint4*)(t1 + base) = tw;
  }
}

__device__ inline void step_write(const unsigned short* __restrict__ prevb,
                                  unsigned short* __restrict__ nextb,
                                  size_t base, const float s[8]) {
  uint4 pv = *(const uint4*)(prevb + base);
  uint4 nw;
  nw.x = pack2(2.0f * s[0] - u2f_lo(pv.x), 2.0f * s[1] - u2f_hi(pv.x));
  nw.y = pack2(2.0f * s[2] - u2f_lo(pv.y), 2.0f * s[3] - u2f_hi(pv.y));
  nw.z = pack2(2.0f * s[4] - u2f_lo(pv.z), 2.0f * s[5] - u2f_hi(pv.z));
  nw.w = pack2(2.0f * s[6] - u2f_lo(pv.w), 2.0f * s[7] - u2f_hi(pv.w));
  *(uint4*)(nextb + base) = nw;
}

__global__ void spmm_step(const int* __restrict__ rowptr, const int2* __restrict__ ecw,
                          const unsigned short* __restrict__ curb,
                          const unsigned short* __restrict__ prevb,
                          unsigned short* __restrict__ nextb, int n) {
  int wv = (blockIdx.x * blockDim.x + threadIdx.x) >> 6;
  int lane = threadIdx.x & 63;
  int p = lane & 7, g = lane >> 3;
  int rowA = wv * 2;
  if (rowA >= n) return;
  int rowB = rowA + 1;
  bool hasB = rowB < n;
  float sA[8], sB[8];
  gather_two(rowptr, ecw, curb, rowA, hasB ? rowB : rowA, hasB, p, g, sA, sB);
  if (g == 0)
    step_write(prevb, nextb, (size_t)rowA * NCLS + (p << 3), sA);
  if (g == 1 && hasB)
    step_write(prevb, nextb, (size_t)rowB * NCLS + (p << 3), sB);
}

// ---- final: v = sum_k cw[k]*T_k, then log-softmax, write fp32 out ----
__global__ void final_comb(const unsigned short* __restrict__ T, size_t tstride,
                           const float* __restrict__ cw, float* __restrict__ out, int n) {
  int wv = (blockIdx.x * blockDim.x + threadIdx.x) >> 6;
  int ch = threadIdx.x & 63;
  if (wv >= n) return;
  size_t idx = (size_t)wv * NCLS + ch;
  float v = 0.0f;
#pragma unroll
  for (int k = 0; k <= KPOLY; ++k) {
    unsigned short tv = T[(size_t)k * tstride + idx];
    v = fmaf(cw[k], __uint_as_float(((unsigned)tv) << 16), v);
  }
  float m = v;
#pragma unroll
  for (int off = 32; off > 0; off >>= 1) m = fmaxf(m, __shfl_xor(m, off, 64));
  float ex = expf(v - m);
  float ss = ex;
#pragma unroll
  for (int off = 32; off > 0; off >>= 1) ss += __shfl_xor(ss, off, 64);
  out[idx] = v - m - logf(ss);
}

// ------------------------- launch -------------------------
extern "C" void kernel_launch(void* const* d_in, const int* in_sizes, int n_in,
                              void* d_out, int out_size, void* d_ws, size_t ws_size,
                              hipStream_t stream) {
  const float* x  = (const float*)d_in[0];
  const int*   ei = (const int*)d_in[1];
  const float* W1 = (const float*)d_in[2];
  const float* W2 = (const float*)d_in[3];
  const float* cw = (const float*)d_in[4];
  float* out = (float*)d_out;

  const int n = in_sizes[0] / NFEAT;     // 100000
  const int E = in_sizes[1] / 2;         // 1600000

  size_t off = 0;
  auto alloc = [&](size_t bytes) { size_t o = off; off += (bytes + 255) & ~(size_t)255; return o; };
  char* w = (char*)d_ws;
  size_t o_cnt   = alloc((size_t)n * 4);
  size_t o_self  = alloc((size_t)n * 4);
  size_t o_cur   = alloc((size_t)n * 4);
  size_t o_dinv  = alloc((size_t)n * 4);      // memset region: o_cnt .. o_dinv
  size_t o_rp    = alloc((size_t)(n + 1) * 4);
  size_t o_bs    = alloc(4096 * 4);
  size_t o_w1f   = alloc((size_t)KPAD * NHID * 2);
  size_t o_w2f   = alloc((size_t)NHID * NCLS * 2);
  size_t o_ecw   = alloc((size_t)E * 8);
  const size_t tsz_b = (((size_t)n * NCLS * 2) + 255) & ~(size_t)255;
  size_t o_T     = alloc(tsz_b * (KPOLY + 1));
  const size_t tstride = tsz_b / 2;

  int*   cnt    = (int*)(w + o_cnt);
  int*   selfc  = (int*)(w + o_self);
  int*   curi   = (int*)(w + o_cur);
  float* dinv   = (float*)(w + o_dinv);
  int*   rowptr = (int*)(w + o_rp);
  int*   bsums  = (int*)(w + o_bs);
  unsigned short* W1F = (unsigned short*)(w + o_w1f);
  unsigned short* W2F = (unsigned short*)(w + o_w2f);
  int2*  ecw    = (int2*)(w + o_ecw);
  unsigned short* T = (unsigned short*)(w + o_T);
  auto Tk = [&](int k) { return T + (size_t)k * tstride; };

  hipMemsetAsync(w + o_cnt, 0, o_dinv - o_cnt, stream);

  const int nb = (n + 255) / 256;

  conv_w1f<<<(KPAD * NHID + 255) / 256, 256, 0, stream>>>(W1, W1F);
  conv_w2f<<<(NHID * NCLS + 255) / 256, 256, 0, stream>>>(W2, W2F);

  edge_count<<<1024, 256, 0, stream>>>(ei, E, cnt, selfc);
  make_dinv<<<nb, 256, 0, stream>>>(cnt, selfc, dinv, n);
  scan_block<<<nb, 256, 0, stream>>>(cnt, rowptr, bsums, n);
  scan_sums<<<1, 1, 0, stream>>>(bsums, nb, rowptr);
  scan_add<<<nb, 256, 0, stream>>>(rowptr, bsums, n);
  scatter_edges<<<1024, 256, 0, stream>>>(ei, E, dinv, rowptr, curi, ecw);

  mlp_mfma<<<(n + 63) / 64, 256, 0, stream>>>(x, W1F, W2F, Tk(0), n);

  const int waves = (n + 1) / 2;
  const int spmm_blocks = (waves + 3) / 4;
  spmm_first<<<spmm_blocks, 256, 0, stream>>>(rowptr, ecw, Tk(0), Tk(1), n);
  for (int k = 2; k <= KPOLY; ++k) {
    spmm_step<<<spmm_blocks, 256, 0, stream>>>(rowptr, ecw, Tk(k - 1), Tk(k - 2), Tk(k), n);
  }

  final_comb<<<(n + 3) / 4, 256, 0, stream>>>(T, tstride, cw, out, n);
}